// Round 10
// baseline (166.865 us; speedup 1.0000x reference)
//
#include <hip/hip_runtime.h>

#define MB    32        // B*T slices
#define CCH   256       // channels C
#define QCH   32        // q/k channels
#define NPIX  1024      // W*H
#define SLICE (CCH * NPIX)   // 262144
#define L2E   1.44269504088896340736f
#define SHIFT 32.0f     // fixed softmax shift (log2-domain energies well within fp32 range)

typedef __bf16          bf16x8 __attribute__((ext_vector_type(8)));
typedef __bf16          bf16x4 __attribute__((ext_vector_type(4)));
typedef float           f32x4  __attribute__((ext_vector_type(4)));
typedef unsigned int    u32x4  __attribute__((ext_vector_type(4)));
typedef unsigned short  u16x4  __attribute__((ext_vector_type(4)));

__device__ __forceinline__ unsigned short f2bf(float f) {
    unsigned int u = __builtin_bit_cast(unsigned int, f);
    u += 0x7FFFu + ((u >> 16) & 1u);          // RTNE
    return (unsigned short)(u >> 16);
}
__device__ __forceinline__ u16x4 cvt4(float a, float b, float c, float d) {
    bf16x4 v = { (__bf16)a, (__bf16)b, (__bf16)c, (__bf16)d };   // v_cvt_pk_bf16_f32
    return __builtin_bit_cast(u16x4, v);
}
__device__ __forceinline__ float bf2f(unsigned short u) {
    unsigned int v = (unsigned int)u << 16;
    return __builtin_bit_cast(float, v);
}
__device__ __forceinline__ bf16x8 ldfrag(const unsigned short* p) {
    u32x4 u = *(const u32x4*)p;
    return __builtin_bit_cast(bf16x8, u);
}

// workspace byte offsets (Pu eliminated — total need ~21.4 MB)
#define WB_OFF  0u              // 320*256 bf16 = 163840
#define QT_OFF  262144u         // 2 MB
#define KT_OFF  2359296u        // 2 MB
#define V_OFF   4456448u        // 16 MB (MFMA A-frag layout)
#define S_OFF   21233664u       // 128 KB row sums S (f32)

// ---------------------------------------------------------------------------
// K0w (r11-verified): convert stacked [wq;wk;wv] (320x256 f32) -> Wb bf16,
// AND zero the row-sum buffer S[MB*NPIX] (32768 f32). Grid 128x256.
// ---------------------------------------------------------------------------
__global__ __launch_bounds__(256) void k_prep_w(
    const float* __restrict__ wq, const float* __restrict__ wk,
    const float* __restrict__ wv, unsigned short* __restrict__ Wb,
    float* __restrict__ S)
{
    int tid = blockIdx.x * 256 + threadIdx.x;
    S[tid] = 0.0f;
    int i4 = tid * 4;
    if (i4 < 320 * CCH) {
        int o = i4 >> 8, c = i4 & 255;
        const float* src = (o < 32) ? wq + (size_t)o * CCH + c
                         : (o < 64) ? wk + (size_t)(o - 32) * CCH + c
                                    : wv + (size_t)(o - 64) * CCH + c;
        float4 v = *(const float4*)src;
        *(u16x4*)(Wb + i4) = cvt4(v.x, v.y, v.z, v.w);
    }
}

// ---------------------------------------------------------------------------
// K1 (r7-verified, unchanged): MFMA projections with fused x transpose+cvt.
// V sub-tiles use swapped MFMA operands -> coalesced 8B frag stores.
// ---------------------------------------------------------------------------
__global__ __launch_bounds__(256) void k_proj(
    const float* __restrict__ x, const unsigned short* __restrict__ Wb,
    const float* __restrict__ bq, const float* __restrict__ bk,
    const float* __restrict__ bv,
    unsigned short* __restrict__ Qt, unsigned short* __restrict__ Kt,
    unsigned short* __restrict__ V)
{
    __shared__ unsigned short Xs[64 * 268];   // [n][k256], pitch 268

    const int t = threadIdx.x, lane = t & 63, w = t >> 6;
    const int lj = lane & 15, q = lane >> 4;
    const int n0 = blockIdx.x * 64;
    const int mi = blockIdx.y;
    const float* xp = x + (size_t)mi * SLICE;

    // stage + transpose + cvt (c-pairs -> packed u32 LDS writes)
#pragma unroll
    for (int r = 0; r < 8; ++r) {
        int job = t + r * 256;          // 0..2047
        int cp = job >> 4;              // c-pair 0..127
        int seg = job & 15;             // 4-wide n segment
        float4 va = *(const float4*)(xp + (size_t)(2 * cp) * NPIX + n0 + seg * 4);
        float4 vb = *(const float4*)(xp + (size_t)(2 * cp + 1) * NPIX + n0 + seg * 4);
        u16x4 da = cvt4(va.x, va.y, va.z, va.w);
        u16x4 db = cvt4(vb.x, vb.y, vb.z, vb.w);
#pragma unroll
        for (int e = 0; e < 4; ++e) {
            unsigned pk = (unsigned)da[e] | ((unsigned)db[e] << 16);
            *(unsigned*)&Xs[(seg * 4 + e) * 268 + 2 * cp] = pk;
        }
    }
    __syncthreads();

    f32x4 acc[5][4];
#pragma unroll
    for (int i = 0; i < 5; ++i)
#pragma unroll
        for (int b = 0; b < 4; ++b) acc[i][b] = (f32x4){0.f, 0.f, 0.f, 0.f};

    const unsigned short* wbase = Wb + (size_t)(w * 16 + lj) * CCH + q * 8;
    const unsigned short* xbase = &Xs[lj * 268 + q * 8];

#pragma unroll 2
    for (int kc = 0; kc < CCH; kc += 32) {
        bf16x8 a[5];
#pragma unroll
        for (int i = 0; i < 5; ++i)
            a[i] = ldfrag(wbase + (size_t)i * 64 * CCH + kc);
        bf16x8 xb[4];
#pragma unroll
        for (int b = 0; b < 4; ++b)
            xb[b] = ldfrag(xbase + b * 16 * 268 + kc);
#pragma unroll
        for (int i = 0; i < 5; ++i)
#pragma unroll
            for (int b = 0; b < 4; ++b)
                acc[i][b] = (i == 0)
                    ? __builtin_amdgcn_mfma_f32_16x16x32_bf16(a[i], xb[b], acc[i][b], 0, 0, 0)
                    : __builtin_amdgcn_mfma_f32_16x16x32_bf16(xb[b], a[i], acc[i][b], 0, 0, 0);
    }

#pragma unroll
    for (int i = 0; i < 5; ++i) {
        if (i == 0) {
            const int ob = w * 16 + 4 * q;
            if (w < 2) {                   // Q -> Qt[n][o], pre-scaled by log2(e)
                unsigned short* Qp = Qt + (size_t)mi * NPIX * QCH;
                float b0 = bq[ob], b1 = bq[ob + 1], b2 = bq[ob + 2], b3 = bq[ob + 3];
#pragma unroll
                for (int b = 0; b < 4; ++b) {
                    int n = n0 + b * 16 + lj;
                    *(u16x4*)(Qp + (size_t)n * QCH + ob) =
                        cvt4((acc[i][b][0] + b0) * L2E, (acc[i][b][1] + b1) * L2E,
                             (acc[i][b][2] + b2) * L2E, (acc[i][b][3] + b3) * L2E);
                }
            } else {                       // K -> Kt[n][o]
                unsigned short* Kp = Kt + (size_t)mi * NPIX * QCH;
                int o2 = ob - 32;
                float b0 = bk[o2], b1 = bk[o2 + 1], b2 = bk[o2 + 2], b3 = bk[o2 + 3];
#pragma unroll
                for (int b = 0; b < 4; ++b) {
                    int n = n0 + b * 16 + lj;
                    *(u16x4*)(Kp + (size_t)n * QCH + o2) =
                        cvt4(acc[i][b][0] + b0, acc[i][b][1] + b1,
                             acc[i][b][2] + b2, acc[i][b][3] + b3);
                }
            }
        } else {                           // V (swapped): thread = (c=c16*16+lj, n=n0+b*16+4q+r)
            unsigned short* Vw = V + (size_t)mi * SLICE;
            const int c16 = w + 4 * (i - 1);
            const float bb = bv[c16 * 16 + lj];
            const int n05 = n0 >> 5;
#pragma unroll
            for (int b = 0; b < 4; ++b) {
                const int l = lj | (((b & 1) * 2 + (q >> 1)) << 4);
                size_t base = ((size_t)(c16 * 32 + n05 + (b >> 1)) * 64 + l) * 8 + (q & 1) * 4;
                *(u16x4*)(Vw + base) = cvt4(acc[i][b][0] + bb, acc[i][b][1] + bb,
                                            acc[i][b][2] + bb, acc[i][b][3] + bb);
            }
        }
    }
}

// ---------------------------------------------------------------------------
// K2 (r13): row sums S only. Grid (64, MB) = 2048 blocks = 8/CU.
// QK + exp2 + shfl-reduce + one atomicAdd per row per j-eighth.
// ---------------------------------------------------------------------------
__global__ __launch_bounds__(256) void k_sums(
    const unsigned short* __restrict__ Qt, const unsigned short* __restrict__ Kt,
    float* __restrict__ S)
{
    const int t = threadIdx.x, lane = t & 63, w = t >> 6;
    const int lj = lane & 15, q = lane >> 4;
    const int nb = blockIdx.x >> 3;            // n128 block 0..7
    const int jh = blockIdx.x & 7;             // j-eighth 0..7
    const int nw = nb * 128 + w * 32;
    const int mi = blockIdx.y;
    const unsigned short* Qp = Qt + (size_t)mi * NPIX * QCH;
    const unsigned short* Kp = Kt + (size_t)mi * NPIX * QCH;

    bf16x8 qa[2];
#pragma unroll
    for (int h = 0; h < 2; ++h)
        qa[h] = ldfrag(Qp + (size_t)(nw + h * 16 + lj) * QCH + q * 8);

    float s[2][4];
#pragma unroll
    for (int h = 0; h < 2; ++h)
#pragma unroll
        for (int r = 0; r < 4; ++r) s[h][r] = 0.f;

    const int jbeg = jh * 128;
#pragma unroll 4
    for (int jc = jbeg; jc < jbeg + 128; jc += 16) {
        bf16x8 kb = ldfrag(Kp + (size_t)(jc + lj) * QCH + q * 8);
#pragma unroll
        for (int h = 0; h < 2; ++h) {
            f32x4 z = (f32x4){0.f, 0.f, 0.f, 0.f};
            f32x4 e = __builtin_amdgcn_mfma_f32_16x16x32_bf16(qa[h], kb, z, 0, 0, 0);
#pragma unroll
            for (int r = 0; r < 4; ++r) s[h][r] += exp2f(e[r] - SHIFT);
        }
    }

#pragma unroll
    for (int msk = 1; msk <= 8; msk <<= 1)
#pragma unroll
        for (int h = 0; h < 2; ++h)
#pragma unroll
            for (int r = 0; r < 4; ++r) s[h][r] += __shfl_xor(s[h][r], msk, 64);
    if (lj == 0) {
        float* Sp = S + (size_t)mi * NPIX;
#pragma unroll
        for (int h = 0; h < 2; ++h)
#pragma unroll
            for (int r = 0; r < 4; ++r)
                atomicAdd(&Sp[nw + h * 16 + 4 * q + r], s[h][r]);
    }
}

// ---------------------------------------------------------------------------
// K3 (r14 = r13 with the double-normalization bug fixed): fused
// attention+output, j-split for occupancy without QK duplication.
// Grid 16 j x 2 cb x 32 mi = 1024 = 4 blocks/CU. Per wave: j16, K frag in
// regs, Ps[16][36], acc[8]. Normalization applied ONCE: P = exp2(e-SHIFT)
// * rs[n]; V staged RAW (r13 bug: V was also vscale'd -> double 1/S).
// ---------------------------------------------------------------------------
__global__ __launch_bounds__(256, 4) void k_fused2(
    const float* __restrict__ x, const float* __restrict__ gamma,
    const unsigned short* __restrict__ Qt, const unsigned short* __restrict__ Kt,
    const unsigned short* __restrict__ Vf, const float* __restrict__ S,
    float* __restrict__ out)
{
    __shared__ unsigned short Vs[2][4096];    // dbuf: 8 c-frags x 1KB per buf
    __shared__ unsigned short Ps[4][16][36];  // wave-private [j16][n32], pitch 36
    __shared__ float rs[NPIX];                // 1/S_n for this mi (4 KB)

    const int b = blockIdx.x;                 // 0..1023
    const int mi  = (b & 7) | ((b >> 8) << 3);
    const int mid = (b >> 3) & 31;
    const int j0  = (mid & 15) * 64;
    const int cb  = mid >> 4;                 // 0..1 (128 channels each)

    const int t = threadIdx.x, lane = t & 63, w = t >> 6;
    const int lj = lane & 15, q = lane >> 4;
    const int jw = j0 + w * 16;

    const unsigned short* Qp = Qt + (size_t)mi * NPIX * QCH;
    const unsigned short* Kp = Kt + (size_t)mi * NPIX * QCH;
    const unsigned short* Vp = Vf + (size_t)mi * SLICE;
    const float* Sp = S + (size_t)mi * NPIX;

#pragma unroll
    for (int k = 0; k < 4; ++k)
        rs[t + k * 256] = 1.0f / Sp[t + k * 256];

    // K fragment for this wave's j16 window — held in registers all kernel
    bf16x8 kb = ldfrag(Kp + (size_t)(jw + lj) * QCH + q * 8);

    const int ctl = t >> 5, ln0 = (t & 31) * 2;
    const unsigned short* vsrc0 = Vp + ((size_t)(cb * 8 + ctl) * 32) * 512 + ln0 * 8;

    f32x4 acc[8];
#pragma unroll
    for (int ci = 0; ci < 8; ++ci) acc[ci] = (f32x4){0.f, 0.f, 0.f, 0.f};

    // prestage chunk 0 (RAW — normalization lives in P only)
    {
        u32x4 d0 = *(const u32x4*)vsrc0;
        u32x4 d1 = *(const u32x4*)(vsrc0 + 8);
        *(u32x4*)&Vs[0][ctl * 512 + ln0 * 8] = d0;
        *(u32x4*)&Vs[0][ctl * 512 + ln0 * 8 + 8] = d1;
    }
    bf16x8 qa_n[2];
#pragma unroll
    for (int sn = 0; sn < 2; ++sn)
        qa_n[sn] = ldfrag(Qp + (size_t)(sn * 16 + lj) * QCH + q * 8);
    __syncthreads();                          // rs + Vs[0] ready

    int p = 0;
    for (int nc = 0; nc < NPIX; nc += 32, p ^= 1) {
        const int nn = (nc + 32) & (NPIX - 1);
        // prefetch next V chunk (raw)
        const unsigned short* vsrc = vsrc0 + (size_t)(nn >> 5) * 512;
        u32x4 nv0 = *(const u32x4*)vsrc;
        u32x4 nv1 = *(const u32x4*)(vsrc + 8);

        // QK^T + normalized exp2 for this chunk (n32 x j16 per wave)
        bf16x8 qa0 = qa_n[0], qa1 = qa_n[1];
        f32x4 rv0 = *(const f32x4*)&rs[nc + 4 * q];
        f32x4 rv1 = *(const f32x4*)&rs[nc + 16 + 4 * q];
        {
            f32x4 z = (f32x4){0.f, 0.f, 0.f, 0.f};
            f32x4 e0 = __builtin_amdgcn_mfma_f32_16x16x32_bf16(qa0, kb, z, 0, 0, 0);
            f32x4 e1 = __builtin_amdgcn_mfma_f32_16x16x32_bf16(qa1, kb, z, 0, 0, 0);
            *(u16x4*)&Ps[w][lj][4 * q] =
                cvt4(exp2f(e0[0] - SHIFT) * rv0[0], exp2f(e0[1] - SHIFT) * rv0[1],
                     exp2f(e0[2] - SHIFT) * rv0[2], exp2f(e0[3] - SHIFT) * rv0[3]);
            *(u16x4*)&Ps[w][lj][16 + 4 * q] =
                cvt4(exp2f(e1[0] - SHIFT) * rv1[0], exp2f(e1[1] - SHIFT) * rv1[1],
                     exp2f(e1[2] - SHIFT) * rv1[2], exp2f(e1[3] - SHIFT) * rv1[3]);
        }
        // prefetch next Q frags
#pragma unroll
        for (int sn = 0; sn < 2; ++sn)
            qa_n[sn] = ldfrag(Qp + (size_t)(nn + sn * 16 + lj) * QCH + q * 8);

        // PV: read P back as B-frag, 8 MFMA
        bf16x8 pf = ldfrag(&Ps[w][lj][q * 8]);
        __builtin_amdgcn_s_setprio(1);
#pragma unroll
        for (int ci = 0; ci < 8; ++ci) {
            bf16x8 vfr = ldfrag(&Vs[p][ci * 512 + lane * 8]);
            acc[ci] = __builtin_amdgcn_mfma_f32_16x16x32_bf16(vfr, pf, acc[ci], 0, 0, 0);
        }
        __builtin_amdgcn_s_setprio(0);

        // stage next V chunk (raw)
        *(u32x4*)&Vs[p ^ 1][ctl * 512 + ln0 * 8] = nv0;
        *(u32x4*)&Vs[p ^ 1][ctl * 512 + ln0 * 8 + 8] = nv1;
        __syncthreads();
    }

    const float g = gamma[0];
    const size_t obase = (size_t)mi * SLICE;
#pragma unroll
    for (int ci = 0; ci < 8; ++ci) {
#pragma unroll
        for (int r = 0; r < 4; ++r) {
            int c = cb * 128 + ci * 16 + 4 * q + r;
            int j = jw + lj;
            size_t off = obase + (size_t)c * NPIX + j;
            out[off] = g * acc[ci][r] + x[off];
        }
    }
}

extern "C" void kernel_launch(void* const* d_in, const int* in_sizes, int n_in,
                              void* d_out, int out_size, void* d_ws, size_t ws_size,
                              hipStream_t stream)
{
    const float* x     = (const float*)d_in[0];
    const float* wq    = (const float*)d_in[1];
    const float* bq    = (const float*)d_in[2];
    const float* wk    = (const float*)d_in[3];
    const float* bk    = (const float*)d_in[4];
    const float* wv    = (const float*)d_in[5];
    const float* bv    = (const float*)d_in[6];
    const float* gamma = (const float*)d_in[7];
    float* out = (float*)d_out;

    char* wsb = (char*)d_ws;
    unsigned short* Wb = (unsigned short*)(wsb + WB_OFF);
    unsigned short* Qt = (unsigned short*)(wsb + QT_OFF);
    unsigned short* Kt = (unsigned short*)(wsb + KT_OFF);
    unsigned short* V  = (unsigned short*)(wsb + V_OFF);
    float*          Sa = (float*)(wsb + S_OFF);

    k_prep_w<<<128, 256, 0, stream>>>(wq, wk, wv, Wb, Sa);
    k_proj<<<dim3(NPIX / 64, MB), 256, 0, stream>>>(x, Wb, bq, bk, bv, Qt, Kt, V);
    k_sums<<<dim3(64, MB), 256, 0, stream>>>(Qt, Kt, Sa);
    k_fused2<<<1024, 256, 0, stream>>>(x, gamma, Qt, Kt, V, Sa, out);
}

// Round 11
// 156.301 us; speedup vs baseline: 1.0676x; 1.0676x over previous
//
#include <hip/hip_runtime.h>

#define MB    32        // B*T slices
#define CCH   256       // channels C
#define QCH   32        // q/k channels
#define NPIX  1024      // W*H
#define SLICE (CCH * NPIX)   // 262144
#define L2E   1.44269504088896340736f
#define SHIFT 32.0f     // fixed softmax shift (log2-domain energies well within fp32 range)

typedef __bf16          bf16x8 __attribute__((ext_vector_type(8)));
typedef __bf16          bf16x4 __attribute__((ext_vector_type(4)));
typedef float           f32x4  __attribute__((ext_vector_type(4)));
typedef unsigned int    u32x4  __attribute__((ext_vector_type(4)));
typedef unsigned short  u16x4  __attribute__((ext_vector_type(4)));

#define XP 270          // Xs pitch (u16): 135 dw == 7 mod 32 -> 2-way (free) stage writes

__device__ __forceinline__ unsigned short f2bf(float f) {
    unsigned int u = __builtin_bit_cast(unsigned int, f);
    u += 0x7FFFu + ((u >> 16) & 1u);          // RTNE
    return (unsigned short)(u >> 16);
}
__device__ __forceinline__ u16x4 cvt4(float a, float b, float c, float d) {
    bf16x4 v = { (__bf16)a, (__bf16)b, (__bf16)c, (__bf16)d };   // v_cvt_pk_bf16_f32
    return __builtin_bit_cast(u16x4, v);
}
__device__ __forceinline__ float bf2f(unsigned short u) {
    unsigned int v = (unsigned int)u << 16;
    return __builtin_bit_cast(float, v);
}
__device__ __forceinline__ bf16x8 ldfrag(const unsigned short* p) {
    u32x4 u = *(const u32x4*)p;
    return __builtin_bit_cast(bf16x8, u);
}
// scale 8 bf16 (one V-frag lane) by r8[0..7], repack (RTNE)
__device__ __forceinline__ u32x4 vscale(u32x4 d, const float* __restrict__ r8) {
    const unsigned short* ds = (const unsigned short*)&d;
    u16x4 a = cvt4(bf2f(ds[0]) * r8[0], bf2f(ds[1]) * r8[1],
                   bf2f(ds[2]) * r8[2], bf2f(ds[3]) * r8[3]);
    u16x4 b = cvt4(bf2f(ds[4]) * r8[4], bf2f(ds[5]) * r8[5],
                   bf2f(ds[6]) * r8[6], bf2f(ds[7]) * r8[7]);
    u32x4 o;
    ((u16x4*)&o)[0] = a;
    ((u16x4*)&o)[1] = b;
    return o;
}

// workspace byte offsets
#define WB_OFF  0u              // 320*256 bf16 = 163840
#define QT_OFF  262144u         // 2 MB
#define KT_OFF  2359296u        // 2 MB
#define V_OFF   4456448u        // 16 MB (MFMA A-frag layout)
#define A2F_OFF 21233664u       // 128 KB: primary = row sums S (f32); fallback = log-sums a2f
#define PU_OFF  21364736u       // 64 MB (primary path only: UNNORMALIZED Pu B-frags)
#define WS_NEED 88473600u

// ---------------------------------------------------------------------------
// K0w (r11-verified): convert stacked [wq;wk;wv] (320x256 f32) -> Wb bf16,
// AND zero the row-sum buffer S[MB*NPIX] (32768 f32). Grid 128x256.
// ---------------------------------------------------------------------------
__global__ __launch_bounds__(256) void k_prep_w(
    const float* __restrict__ wq, const float* __restrict__ wk,
    const float* __restrict__ wv, unsigned short* __restrict__ Wb,
    float* __restrict__ S)
{
    int tid = blockIdx.x * 256 + threadIdx.x;
    S[tid] = 0.0f;
    int i4 = tid * 4;
    if (i4 < 320 * CCH) {
        int o = i4 >> 8, c = i4 & 255;
        const float* src = (o < 32) ? wq + (size_t)o * CCH + c
                         : (o < 64) ? wk + (size_t)(o - 32) * CCH + c
                                    : wv + (size_t)(o - 64) * CCH + c;
        float4 v = *(const float4*)src;
        *(u16x4*)(Wb + i4) = cvt4(v.x, v.y, v.z, v.w);
    }
}

// ---------------------------------------------------------------------------
// K1 (r7-verified + r15 pitch fix): MFMA projections with fused x
// transpose+cvt. Xs pitch 268->270: staging-write bank conflicts 4-way ->
// 2-way (free); frag reads stay <=2-way.
// ---------------------------------------------------------------------------
__global__ __launch_bounds__(256) void k_proj(
    const float* __restrict__ x, const unsigned short* __restrict__ Wb,
    const float* __restrict__ bq, const float* __restrict__ bk,
    const float* __restrict__ bv,
    unsigned short* __restrict__ Qt, unsigned short* __restrict__ Kt,
    unsigned short* __restrict__ V)
{
    __shared__ unsigned short Xs[64 * XP];    // [n][k256], pitch XP=270

    const int t = threadIdx.x, lane = t & 63, w = t >> 6;
    const int lj = lane & 15, q = lane >> 4;
    const int n0 = blockIdx.x * 64;
    const int mi = blockIdx.y;
    const float* xp = x + (size_t)mi * SLICE;

    // stage + transpose + cvt (c-pairs -> packed u32 LDS writes)
#pragma unroll
    for (int r = 0; r < 8; ++r) {
        int job = t + r * 256;          // 0..2047
        int cp = job >> 4;              // c-pair 0..127
        int seg = job & 15;             // 4-wide n segment
        float4 va = *(const float4*)(xp + (size_t)(2 * cp) * NPIX + n0 + seg * 4);
        float4 vb = *(const float4*)(xp + (size_t)(2 * cp + 1) * NPIX + n0 + seg * 4);
        u16x4 da = cvt4(va.x, va.y, va.z, va.w);
        u16x4 db = cvt4(vb.x, vb.y, vb.z, vb.w);
#pragma unroll
        for (int e = 0; e < 4; ++e) {
            unsigned pk = (unsigned)da[e] | ((unsigned)db[e] << 16);
            *(unsigned*)&Xs[(seg * 4 + e) * XP + 2 * cp] = pk;
        }
    }
    __syncthreads();

    f32x4 acc[5][4];
#pragma unroll
    for (int i = 0; i < 5; ++i)
#pragma unroll
        for (int b = 0; b < 4; ++b) acc[i][b] = (f32x4){0.f, 0.f, 0.f, 0.f};

    const unsigned short* wbase = Wb + (size_t)(w * 16 + lj) * CCH + q * 8;
    const unsigned short* xbase = &Xs[lj * XP + q * 8];

#pragma unroll 2
    for (int kc = 0; kc < CCH; kc += 32) {
        bf16x8 a[5];
#pragma unroll
        for (int i = 0; i < 5; ++i)
            a[i] = ldfrag(wbase + (size_t)i * 64 * CCH + kc);
        bf16x8 xb[4];
#pragma unroll
        for (int b = 0; b < 4; ++b)
            xb[b] = ldfrag(xbase + b * 16 * XP + kc);
#pragma unroll
        for (int i = 0; i < 5; ++i)
#pragma unroll
            for (int b = 0; b < 4; ++b)
                acc[i][b] = (i == 0)
                    ? __builtin_amdgcn_mfma_f32_16x16x32_bf16(a[i], xb[b], acc[i][b], 0, 0, 0)
                    : __builtin_amdgcn_mfma_f32_16x16x32_bf16(xb[b], a[i], acc[i][b], 0, 0, 0);
    }

#pragma unroll
    for (int i = 0; i < 5; ++i) {
        if (i == 0) {
            const int ob = w * 16 + 4 * q;
            if (w < 2) {                   // Q -> Qt[n][o], pre-scaled by log2(e)
                unsigned short* Qp = Qt + (size_t)mi * NPIX * QCH;
                float b0 = bq[ob], b1 = bq[ob + 1], b2 = bq[ob + 2], b3 = bq[ob + 3];
#pragma unroll
                for (int b = 0; b < 4; ++b) {
                    int n = n0 + b * 16 + lj;
                    *(u16x4*)(Qp + (size_t)n * QCH + ob) =
                        cvt4((acc[i][b][0] + b0) * L2E, (acc[i][b][1] + b1) * L2E,
                             (acc[i][b][2] + b2) * L2E, (acc[i][b][3] + b3) * L2E);
                }
            } else {                       // K -> Kt[n][o]
                unsigned short* Kp = Kt + (size_t)mi * NPIX * QCH;
                int o2 = ob - 32;
                float b0 = bk[o2], b1 = bk[o2 + 1], b2 = bk[o2 + 2], b3 = bk[o2 + 3];
#pragma unroll
                for (int b = 0; b < 4; ++b) {
                    int n = n0 + b * 16 + lj;
                    *(u16x4*)(Kp + (size_t)n * QCH + o2) =
                        cvt4(acc[i][b][0] + b0, acc[i][b][1] + b1,
                             acc[i][b][2] + b2, acc[i][b][3] + b3);
                }
            }
        } else {                           // V (swapped): thread = (c=c16*16+lj, n=n0+b*16+4q+r)
            unsigned short* Vw = V + (size_t)mi * SLICE;
            const int c16 = w + 4 * (i - 1);
            const float bb = bv[c16 * 16 + lj];
            const int n05 = n0 >> 5;
#pragma unroll
            for (int b = 0; b < 4; ++b) {
                const int l = lj | (((b & 1) * 2 + (q >> 1)) << 4);
                size_t base = ((size_t)(c16 * 32 + n05 + (b >> 1)) * 64 + l) * 8 + (q & 1) * 4;
                *(u16x4*)(Vw + base) = cvt4(acc[i][b][0] + bb, acc[i][b][1] + bb,
                                            acc[i][b][2] + bb, acc[i][b][3] + bb);
            }
        }
    }
}

// ---------------------------------------------------------------------------
// K2a (fallback only): row log-sums a2[n] = SHIFT + log2(sum_j 2^(e-SHIFT)).
// ---------------------------------------------------------------------------
__global__ __launch_bounds__(256) void k_stats(
    const unsigned short* __restrict__ Qt, const unsigned short* __restrict__ Kt,
    float* __restrict__ a2f)
{
    const int t = threadIdx.x, lane = t & 63, w = t >> 6;
    const int lj = lane & 15, q = lane >> 4;
    const int n16 = blockIdx.x * 64 + w * 16;
    const int mi = blockIdx.y;
    const unsigned short* Qp = Qt + (size_t)mi * NPIX * QCH;
    const unsigned short* Kp = Kt + (size_t)mi * NPIX * QCH;

    bf16x8 qa = ldfrag(Qp + (size_t)(n16 + lj) * QCH + q * 8);

    float s[4] = { 0.f, 0.f, 0.f, 0.f };
#pragma unroll 8
    for (int jc = 0; jc < NPIX; jc += 16) {
        bf16x8 kb = ldfrag(Kp + (size_t)(jc + lj) * QCH + q * 8);
        f32x4 z = (f32x4){0.f, 0.f, 0.f, 0.f};
        f32x4 e = __builtin_amdgcn_mfma_f32_16x16x32_bf16(qa, kb, z, 0, 0, 0);
#pragma unroll
        for (int r = 0; r < 4; ++r) s[r] += exp2f(e[r] - SHIFT);
    }
#pragma unroll
    for (int msk = 1; msk <= 8; msk <<= 1)
#pragma unroll
        for (int r = 0; r < 4; ++r) s[r] += __shfl_xor(s[r], msk, 64);
    if (lj == 0) {
        float* apo = a2f + (size_t)mi * NPIX;
#pragma unroll
        for (int r = 0; r < 4; ++r)
            apo[n16 + 4 * q + r] = SHIFT + log2f(s[r]);
    }
}

// ---------------------------------------------------------------------------
// K2b (primary, r11-verified): UNNORMALIZED Pu = exp2(e - SHIFT) as bf16
// B-frags, accumulating row sums S via shfl-reduce + atomicAdd.
// Grid (32, MB): n128 blocks x j-quarters (r7 = session-best config).
// ---------------------------------------------------------------------------
__global__ __launch_bounds__(256) void k_pu(
    const unsigned short* __restrict__ Qt, const unsigned short* __restrict__ Kt,
    float* __restrict__ S, unsigned short* __restrict__ Pu)
{
    __shared__ unsigned short Ps[4][32][36];   // wave-private [j32][n32], pitch 36

    const int t = threadIdx.x, lane = t & 63, w = t >> 6;
    const int lj = lane & 15, q = lane >> 4;
    const int nb = blockIdx.x >> 2;            // n128 block 0..7
    const int jh = blockIdx.x & 3;             // j-quarter 0..3
    const int nw = nb * 128 + w * 32;
    const int mi = blockIdx.y;
    const unsigned short* Qp = Qt + (size_t)mi * NPIX * QCH;
    const unsigned short* Kp = Kt + (size_t)mi * NPIX * QCH;
    unsigned short* Pup = Pu + (size_t)mi * NPIX * NPIX;

    bf16x8 qa[2];
#pragma unroll
    for (int h = 0; h < 2; ++h)
        qa[h] = ldfrag(Qp + (size_t)(nw + h * 16 + lj) * QCH + q * 8);

    float s[2][4];
#pragma unroll
    for (int h = 0; h < 2; ++h)
#pragma unroll
        for (int r = 0; r < 4; ++r) s[h][r] = 0.f;

    const int jbeg = jh * 256;
#pragma unroll 2
    for (int jc = jbeg; jc < jbeg + 256; jc += 32) {
#pragma unroll
        for (int f = 0; f < 2; ++f) {
            bf16x8 kb = ldfrag(Kp + (size_t)(jc + f * 16 + lj) * QCH + q * 8);
#pragma unroll
            for (int h = 0; h < 2; ++h) {
                f32x4 z = (f32x4){0.f, 0.f, 0.f, 0.f};
                f32x4 e = __builtin_amdgcn_mfma_f32_16x16x32_bf16(qa[h], kb, z, 0, 0, 0);
                float p0 = exp2f(e[0] - SHIFT), p1 = exp2f(e[1] - SHIFT);
                float p2 = exp2f(e[2] - SHIFT), p3 = exp2f(e[3] - SHIFT);
                s[h][0] += p0; s[h][1] += p1; s[h][2] += p2; s[h][3] += p3;
                *(u16x4*)&Ps[w][f * 16 + lj][h * 16 + 4 * q] = cvt4(p0, p1, p2, p3);
            }
        }
        // read back as B-frags (k=n32 x j16) and store to global frag layout
#pragma unroll
        for (int f = 0; f < 2; ++f) {
            u32x4 bfrag = *(const u32x4*)&Ps[w][f * 16 + lj][q * 8];
            *(u32x4*)(Pup + ((size_t)((jc >> 4) + f) * 32 + (nw >> 5)) * 512 + lane * 8) = bfrag;
        }
    }

    // row-sum reduce across the 16 j-lanes (lj), then one atomic per row
#pragma unroll
    for (int msk = 1; msk <= 8; msk <<= 1)
#pragma unroll
        for (int h = 0; h < 2; ++h)
#pragma unroll
            for (int r = 0; r < 4; ++r) s[h][r] += __shfl_xor(s[h][r], msk, 64);
    if (lj == 0) {
        float* Sp = S + (size_t)mi * NPIX;
#pragma unroll
        for (int h = 0; h < 2; ++h)
#pragma unroll
            for (int r = 0; r < 4; ++r)
                atomicAdd(&Sp[nw + h * 16 + 4 * q + r], s[h][r]);
    }
}

// ---------------------------------------------------------------------------
// K3 (primary, r11-verified): fragment GEMM O = (V/S) @ Pu_unnorm + residual.
// 1/S folded into V at LDS staging. cb4 grid 1024, Pu prefetch depth-2.
// ---------------------------------------------------------------------------
__global__ __launch_bounds__(256, 4) void k_gemm_out(
    const float* __restrict__ x, const float* __restrict__ gamma,
    const unsigned short* __restrict__ Vf, const unsigned short* __restrict__ Pu,
    const float* __restrict__ S, float* __restrict__ out)
{
    __shared__ unsigned short Vs[2][4096];   // dbuf: 2 chunks x 4 c-frags x 1KB
    __shared__ float rs[NPIX];               // 1/S_n for this mi (4 KB)

    const int b = blockIdx.x;                // 0..1023
    const int mi  = (b & 7) | ((b >> 8) << 3);
    const int sub = (b >> 3) & 31;
    const int j0  = (sub & 7) * 128;
    const int cb  = sub >> 3;                // 0..3 (64 channels each)

    const int t = threadIdx.x, lane = t & 63, w = t >> 6;
    const int lj = lane & 15, q = lane >> 4;
    const int jw = j0 + w * 32;

    const float* Sp = S + (size_t)mi * NPIX;
#pragma unroll
    for (int k = 0; k < 4; ++k)
        rs[t + k * 256] = 1.0f / Sp[t + k * 256];

    const unsigned short* Vp  = Vf + (size_t)mi * SLICE;
    const unsigned short* Pup = Pu + (size_t)mi * NPIX * NPIX
                              + ((size_t)(jw >> 4) * 32) * 512 + lane * 8;

    const int fs = t >> 5;                   // 0..7 = chunk-half (fs>>2) x c-frag (fs&3)
    const int ln0 = (t & 31) * 2;
    const int g8 = (ln0 >> 4) * 8;           // n_loc base for this thread's frag lanes
    const unsigned short* vsrc0 = Vp
        + ((size_t)((cb * 4 + (fs & 3)) * 32) + (fs >> 2)) * 512 + ln0 * 8;

    f32x4 acc[4][2];
#pragma unroll
    for (int ci = 0; ci < 4; ++ci)
#pragma unroll
        for (int f = 0; f < 2; ++f) acc[ci][f] = (f32x4){0.f, 0.f, 0.f, 0.f};

    __syncthreads();                         // rs ready

    // prestage pair 0 (chunks 0,1), scaled by 1/S
    {
        const float* r8 = &rs[(fs >> 2) * 32 + g8];
        u32x4 d0 = vscale(*(const u32x4*)vsrc0, r8);
        u32x4 d1 = vscale(*(const u32x4*)(vsrc0 + 8), r8);
        *(u32x4*)&Vs[0][fs * 512 + ln0 * 8] = d0;
        *(u32x4*)&Vs[0][fs * 512 + ln0 * 8 + 8] = d1;
    }
    bf16x8 pf[2][2], pfN[2][2];
#pragma unroll
    for (int h = 0; h < 2; ++h)
#pragma unroll
        for (int f = 0; f < 2; ++f) {
            pf[h][f]  = ldfrag(Pup + f * 16384 + (size_t)h * 512);
            pfN[h][f] = ldfrag(Pup + f * 16384 + (size_t)(2 + h) * 512);
        }
    __syncthreads();

    int p = 0;
    for (int nc = 0; nc < NPIX; nc += 64, p ^= 1) {
        const int n1 = (nc + 64) & (NPIX - 1);    // next pair (V staging)
        const int n2 = (nc + 128) & (NPIX - 1);   // pair+2 (Pu prefetch)
        const unsigned short* vs = vsrc0 + (size_t)(n1 >> 6) * 1024;
        u32x4 nv0 = *(const u32x4*)vs;
        u32x4 nv1 = *(const u32x4*)(vs + 8);
        bf16x8 pf2[2][2];
#pragma unroll
        for (int h = 0; h < 2; ++h)
#pragma unroll
            for (int f = 0; f < 2; ++f)
                pf2[h][f] = ldfrag(Pup + f * 16384 + ((size_t)(n2 >> 5) + h) * 512);

        // O phase: 16 MFMA
        __builtin_amdgcn_s_setprio(1);
#pragma unroll
        for (int h = 0; h < 2; ++h) {
#pragma unroll
            for (int ci = 0; ci < 4; ++ci) {
                bf16x8 vfr = ldfrag(&Vs[p][(h * 4 + ci) * 512 + lane * 8]);
#pragma unroll
                for (int f = 0; f < 2; ++f)
                    acc[ci][f] = __builtin_amdgcn_mfma_f32_16x16x32_bf16(vfr, pf[h][f], acc[ci][f], 0, 0, 0);
            }
        }
        __builtin_amdgcn_s_setprio(0);

        // scale next V pair by 1/S, then stage
        {
            const float* r8 = &rs[((n1 >> 5) + (fs >> 2)) * 32 + g8];
            nv0 = vscale(nv0, r8);
            nv1 = vscale(nv1, r8);
        }
        *(u32x4*)&Vs[p ^ 1][fs * 512 + ln0 * 8] = nv0;
        *(u32x4*)&Vs[p ^ 1][fs * 512 + ln0 * 8 + 8] = nv1;
        __syncthreads();
#pragma unroll
        for (int h = 0; h < 2; ++h)
#pragma unroll
            for (int f = 0; f < 2; ++f) { pf[h][f] = pfN[h][f]; pfN[h][f] = pf2[h][f]; }
    }

    const float g = gamma[0];
    const size_t obase = (size_t)mi * SLICE;
#pragma unroll
    for (int ci = 0; ci < 4; ++ci) {
#pragma unroll
        for (int f = 0; f < 2; ++f) {
#pragma unroll
            for (int r = 0; r < 4; ++r) {
                int c = cb * 64 + ci * 16 + 4 * q + r;
                int j = jw + f * 16 + lj;
                size_t off = obase + (size_t)c * NPIX + j;
                out[off] = g * acc[ci][f][r] + x[off];
            }
        }
    }
}

// ---------------------------------------------------------------------------
// Fallback K3 (r5-verified) for small ws_size: recompute E, exp2(e - a2).
// ---------------------------------------------------------------------------
__global__ __launch_bounds__(256) void k_attn_out(
    const float* __restrict__ x, const float* __restrict__ gamma,
    const unsigned short* __restrict__ Qt, const unsigned short* __restrict__ Kt,
    const unsigned short* __restrict__ Vf, const float* __restrict__ a2f,
    float* __restrict__ out)
{
    __shared__ unsigned short Vs[2][8 * 512];
    __shared__ unsigned short Ps[4][32][36];

    const int b = blockIdx.x;
    const int mi  = (b & 7) | ((b >> 7) << 3);
    const int sub = (b >> 3) & 15;
    const int j0  = (sub & 7) * 128;
    const int cb  = sub >> 3;

    const int t = threadIdx.x, lane = t & 63, w = t >> 6;
    const int lj = lane & 15, q = lane >> 4;
    const int jw = j0 + w * 32;

    const unsigned short* Qp = Qt + (size_t)mi * NPIX * QCH;
    const unsigned short* Kp = Kt + (size_t)mi * NPIX * QCH;
    const unsigned short* Vp = Vf + (size_t)mi * SLICE;
    const float* ap = a2f + (size_t)mi * NPIX;

    bf16x8 kb[2];
#pragma unroll
    for (int sj = 0; sj < 2; ++sj)
        kb[sj] = ldfrag(Kp + (size_t)(jw + sj * 16 + lj) * QCH + q * 8);

    const int ctl = t >> 5, ln0 = (t & 31) * 2;
    const unsigned short* vsrc0 = Vp + ((size_t)(cb * 8 + ctl) * 32) * 512 + ln0 * 8;

    f32x4 acc[8][2];
#pragma unroll
    for (int ci = 0; ci < 8; ++ci)
#pragma unroll
        for (int ji = 0; ji < 2; ++ji) acc[ci][ji] = (f32x4){0.f, 0.f, 0.f, 0.f};

    {
        u32x4 d0 = *(const u32x4*)vsrc0;
        u32x4 d1 = *(const u32x4*)(vsrc0 + 8);
        *(u32x4*)&Vs[0][ctl * 512 + ln0 * 8] = d0;
        *(u32x4*)&Vs[0][ctl * 512 + ln0 * 8 + 8] = d1;
    }
    bf16x8 qa_n[2];
    f32x4  a4_n[2];
#pragma unroll
    for (int sn = 0; sn < 2; ++sn) {
        qa_n[sn] = ldfrag(Qp + (size_t)(sn * 16 + lj) * QCH + q * 8);
        a4_n[sn] = *(const f32x4*)(ap + sn * 16 + 4 * q);
    }
    __syncthreads();

    int p = 0;
    for (int nc = 0; nc < NPIX; nc += 32, p ^= 1) {
        const int nn = (nc + 32) & (NPIX - 1);
        const unsigned short* vsrc = vsrc0 + (size_t)(nn >> 5) * 512;
        u32x4 nv0 = *(const u32x4*)vsrc;
        u32x4 nv1 = *(const u32x4*)(vsrc + 8);

        bf16x8 qa0 = qa_n[0], qa1 = qa_n[1];
        f32x4 a40 = a4_n[0], a41 = a4_n[1];
#pragma unroll
        for (int sj = 0; sj < 2; ++sj) {
            f32x4 z = (f32x4){0.f, 0.f, 0.f, 0.f};
            f32x4 e0 = __builtin_amdgcn_mfma_f32_16x16x32_bf16(qa0, kb[sj], z, 0, 0, 0);
            f32x4 e1 = __builtin_amdgcn_mfma_f32_16x16x32_bf16(qa1, kb[sj], z, 0, 0, 0);
            *(u16x4*)&Ps[w][sj * 16 + lj][4 * q] =
                cvt4(exp2f(e0[0] - a40[0]), exp2f(e0[1] - a40[1]),
                     exp2f(e0[2] - a40[2]), exp2f(e0[3] - a40[3]));
            *(u16x4*)&Ps[w][sj * 16 + lj][16 + 4 * q] =
                cvt4(exp2f(e1[0] - a41[0]), exp2f(e1[1] - a41[1]),
                     exp2f(e1[2] - a41[2]), exp2f(e1[3] - a41[3]));
        }
#pragma unroll
        for (int sn = 0; sn < 2; ++sn) {
            qa_n[sn] = ldfrag(Qp + (size_t)(nn + sn * 16 + lj) * QCH + q * 8);
            a4_n[sn] = *(const f32x4*)(ap + nn + sn * 16 + 4 * q);
        }

        bf16x8 pf[2];
#pragma unroll
        for (int ji = 0; ji < 2; ++ji)
            pf[ji] = ldfrag(&Ps[w][ji * 16 + lj][q * 8]);
#pragma unroll
        for (int ci = 0; ci < 8; ++ci) {
            bf16x8 vfr = ldfrag(&Vs[p][ci * 512 + lane * 8]);
#pragma unroll
            for (int ji = 0; ji < 2; ++ji)
                acc[ci][ji] = __builtin_amdgcn_mfma_f32_16x16x32_bf16(vfr, pf[ji], acc[ci][ji], 0, 0, 0);
        }

        *(u32x4*)&Vs[p ^ 1][ctl * 512 + ln0 * 8] = nv0;
        *(u32x4*)&Vs[p ^ 1][ctl * 512 + ln0 * 8 + 8] = nv1;
        __syncthreads();
    }

    const float g = gamma[0];
    const size_t obase = (size_t)mi * SLICE;
#pragma unroll
    for (int ci = 0; ci < 8; ++ci) {
#pragma unroll
        for (int ji = 0; ji < 2; ++ji) {
#pragma unroll
            for (int r = 0; r < 4; ++r) {
                int c = cb * 128 + ci * 16 + 4 * q + r;
                int j = jw + ji * 16 + lj;
                size_t off = obase + (size_t)c * NPIX + j;
                out[off] = g * acc[ci][ji][r] + x[off];
            }
        }
    }
}

extern "C" void kernel_launch(void* const* d_in, const int* in_sizes, int n_in,
                              void* d_out, int out_size, void* d_ws, size_t ws_size,
                              hipStream_t stream)
{
    const float* x     = (const float*)d_in[0];
    const float* wq    = (const float*)d_in[1];
    const float* bq    = (const float*)d_in[2];
    const float* wk    = (const float*)d_in[3];
    const float* bk    = (const float*)d_in[4];
    const float* wv    = (const float*)d_in[5];
    const float* bv    = (const float*)d_in[6];
    const float* gamma = (const float*)d_in[7];
    float* out = (float*)d_out;

    char* wsb = (char*)d_ws;
    unsigned short* Wb = (unsigned short*)(wsb + WB_OFF);
    unsigned short* Qt = (unsigned short*)(wsb + QT_OFF);
    unsigned short* Kt = (unsigned short*)(wsb + KT_OFF);
    unsigned short* V  = (unsigned short*)(wsb + V_OFF);
    float*          Sa = (float*)(wsb + A2F_OFF);   // primary: sums; fallback: log-sums
    unsigned short* Pu = (unsigned short*)(wsb + PU_OFF);

    k_prep_w<<<128, 256, 0, stream>>>(wq, wk, wv, Wb, Sa);
    k_proj<<<dim3(NPIX / 64, MB), 256, 0, stream>>>(x, Wb, bq, bk, bv, Qt, Kt, V);

    if (ws_size >= (size_t)WS_NEED) {
        k_pu<<<dim3(32, MB), 256, 0, stream>>>(Qt, Kt, Sa, Pu);
        k_gemm_out<<<1024, 256, 0, stream>>>(x, gamma, V, Pu, Sa, out);
    } else {
        k_stats<<<dim3(NPIX / 64, MB), 256, 0, stream>>>(Qt, Kt, Sa);
        k_attn_out<<<512, 256, 0, stream>>>(x, gamma, Qt, Kt, V, Sa, out);
    }
}

// Round 12
// 152.831 us; speedup vs baseline: 1.0918x; 1.0227x over previous
//
#include <hip/hip_runtime.h>

#define MB    32        // B*T slices
#define CCH   256       // channels C
#define QCH   32        // q/k channels
#define NPIX  1024      // W*H
#define SLICE (CCH * NPIX)   // 262144
#define L2E   1.44269504088896340736f
#define SHIFT 32.0f     // fixed softmax shift (log2-domain energies well within fp32 range)

typedef __bf16          bf16x8 __attribute__((ext_vector_type(8)));
typedef __bf16          bf16x4 __attribute__((ext_vector_type(4)));
typedef float           f32x4  __attribute__((ext_vector_type(4)));
typedef unsigned int    u32x4  __attribute__((ext_vector_type(4)));
typedef unsigned short  u16x4  __attribute__((ext_vector_type(4)));

#define XP 270          // Xs pitch (u16): 135 dw == 7 mod 32 -> 2-way (free) stage writes

__device__ __forceinline__ unsigned short f2bf(float f) {
    unsigned int u = __builtin_bit_cast(unsigned int, f);
    u += 0x7FFFu + ((u >> 16) & 1u);          // RTNE
    return (unsigned short)(u >> 16);
}
__device__ __forceinline__ u16x4 cvt4(float a, float b, float c, float d) {
    bf16x4 v = { (__bf16)a, (__bf16)b, (__bf16)c, (__bf16)d };   // v_cvt_pk_bf16_f32
    return __builtin_bit_cast(u16x4, v);
}
__device__ __forceinline__ float bf2f(unsigned short u) {
    unsigned int v = (unsigned int)u << 16;
    return __builtin_bit_cast(float, v);
}
__device__ __forceinline__ bf16x8 ldfrag(const unsigned short* p) {
    u32x4 u = *(const u32x4*)p;
    return __builtin_bit_cast(bf16x8, u);
}
// scale 8 bf16 (one V-frag lane) by r8[0..7], repack (RTNE)
__device__ __forceinline__ u32x4 vscale(u32x4 d, const float* __restrict__ r8) {
    const unsigned short* ds = (const unsigned short*)&d;
    u16x4 a = cvt4(bf2f(ds[0]) * r8[0], bf2f(ds[1]) * r8[1],
                   bf2f(ds[2]) * r8[2], bf2f(ds[3]) * r8[3]);
    u16x4 b = cvt4(bf2f(ds[4]) * r8[4], bf2f(ds[5]) * r8[5],
                   bf2f(ds[6]) * r8[6], bf2f(ds[7]) * r8[7]);
    u32x4 o;
    ((u16x4*)&o)[0] = a;
    ((u16x4*)&o)[1] = b;
    return o;
}

// workspace byte offsets
#define WB_OFF  0u              // 320*256 bf16 = 163840
#define QT_OFF  262144u         // 2 MB
#define KT_OFF  2359296u        // 2 MB
#define V_OFF   4456448u        // 16 MB (MFMA A-frag layout)
#define A2F_OFF 21233664u       // 128 KB: primary = row sums S (f32); fallback = log-sums a2f
#define PU_OFF  21364736u       // 64 MB (primary path only: UNNORMALIZED Pu B-frags)
#define WS_NEED 88473600u

// ---------------------------------------------------------------------------
// K0w (r11-verified): convert stacked [wq;wk;wv] (320x256 f32) -> Wb bf16,
// AND zero the row-sum buffer S[MB*NPIX] (32768 f32). Grid 128x256.
// ---------------------------------------------------------------------------
__global__ __launch_bounds__(256) void k_prep_w(
    const float* __restrict__ wq, const float* __restrict__ wk,
    const float* __restrict__ wv, unsigned short* __restrict__ Wb,
    float* __restrict__ S)
{
    int tid = blockIdx.x * 256 + threadIdx.x;
    S[tid] = 0.0f;
    int i4 = tid * 4;
    if (i4 < 320 * CCH) {
        int o = i4 >> 8, c = i4 & 255;
        const float* src = (o < 32) ? wq + (size_t)o * CCH + c
                         : (o < 64) ? wk + (size_t)(o - 32) * CCH + c
                                    : wv + (size_t)(o - 64) * CCH + c;
        float4 v = *(const float4*)src;
        *(u16x4*)(Wb + i4) = cvt4(v.x, v.y, v.z, v.w);
    }
}

// ---------------------------------------------------------------------------
// K1 (r16): MFMA projections with fused x transpose+cvt; K-loop now
// REGISTER DOUBLE-BUFFERED — kc+32's 5 W-frags + 4 Xs-frags issue before
// the 20-MFMA block of kc, hiding L2/LDS latency at this kernel's fixed
// 2 waves/SIMD occupancy. No duplicated work; +~36 VGPR (free at 2 w/SIMD).
// ---------------------------------------------------------------------------
__global__ __launch_bounds__(256) void k_proj(
    const float* __restrict__ x, const unsigned short* __restrict__ Wb,
    const float* __restrict__ bq, const float* __restrict__ bk,
    const float* __restrict__ bv,
    unsigned short* __restrict__ Qt, unsigned short* __restrict__ Kt,
    unsigned short* __restrict__ V)
{
    __shared__ unsigned short Xs[64 * XP];    // [n][k256], pitch XP=270

    const int t = threadIdx.x, lane = t & 63, w = t >> 6;
    const int lj = lane & 15, q = lane >> 4;
    const int n0 = blockIdx.x * 64;
    const int mi = blockIdx.y;
    const float* xp = x + (size_t)mi * SLICE;

    // stage + transpose + cvt (c-pairs -> packed u32 LDS writes)
#pragma unroll
    for (int r = 0; r < 8; ++r) {
        int job = t + r * 256;          // 0..2047
        int cp = job >> 4;              // c-pair 0..127
        int seg = job & 15;             // 4-wide n segment
        float4 va = *(const float4*)(xp + (size_t)(2 * cp) * NPIX + n0 + seg * 4);
        float4 vb = *(const float4*)(xp + (size_t)(2 * cp + 1) * NPIX + n0 + seg * 4);
        u16x4 da = cvt4(va.x, va.y, va.z, va.w);
        u16x4 db = cvt4(vb.x, vb.y, vb.z, vb.w);
#pragma unroll
        for (int e = 0; e < 4; ++e) {
            unsigned pk = (unsigned)da[e] | ((unsigned)db[e] << 16);
            *(unsigned*)&Xs[(seg * 4 + e) * XP + 2 * cp] = pk;
        }
    }
    __syncthreads();

    f32x4 acc[5][4];
#pragma unroll
    for (int i = 0; i < 5; ++i)
#pragma unroll
        for (int b = 0; b < 4; ++b) acc[i][b] = (f32x4){0.f, 0.f, 0.f, 0.f};

    const unsigned short* wbase = Wb + (size_t)(w * 16 + lj) * CCH + q * 8;
    const unsigned short* xbase = &Xs[lj * XP + q * 8];

    // preload kc = 0 fragments
    bf16x8 a0[5], xb0[4];
#pragma unroll
    for (int i = 0; i < 5; ++i)
        a0[i] = ldfrag(wbase + (size_t)i * 64 * CCH);
#pragma unroll
    for (int b = 0; b < 4; ++b)
        xb0[b] = ldfrag(xbase + b * 16 * XP);

#pragma unroll
    for (int kc = 0; kc < CCH; kc += 32) {
        bf16x8 a1[5], xb1[4];
        if (kc + 32 < CCH) {            // compile-time per unrolled iter
#pragma unroll
            for (int i = 0; i < 5; ++i)
                a1[i] = ldfrag(wbase + (size_t)i * 64 * CCH + kc + 32);
#pragma unroll
            for (int b = 0; b < 4; ++b)
                xb1[b] = ldfrag(xbase + b * 16 * XP + kc + 32);
        }
#pragma unroll
        for (int i = 0; i < 5; ++i)
#pragma unroll
            for (int b = 0; b < 4; ++b)
                acc[i][b] = (i == 0)
                    ? __builtin_amdgcn_mfma_f32_16x16x32_bf16(a0[i], xb0[b], acc[i][b], 0, 0, 0)
                    : __builtin_amdgcn_mfma_f32_16x16x32_bf16(xb0[b], a0[i], acc[i][b], 0, 0, 0);
        if (kc + 32 < CCH) {
#pragma unroll
            for (int i = 0; i < 5; ++i) a0[i] = a1[i];
#pragma unroll
            for (int b = 0; b < 4; ++b) xb0[b] = xb1[b];
        }
    }

#pragma unroll
    for (int i = 0; i < 5; ++i) {
        if (i == 0) {
            const int ob = w * 16 + 4 * q;
            if (w < 2) {                   // Q -> Qt[n][o], pre-scaled by log2(e)
                unsigned short* Qp = Qt + (size_t)mi * NPIX * QCH;
                float b0 = bq[ob], b1 = bq[ob + 1], b2 = bq[ob + 2], b3 = bq[ob + 3];
#pragma unroll
                for (int b = 0; b < 4; ++b) {
                    int n = n0 + b * 16 + lj;
                    *(u16x4*)(Qp + (size_t)n * QCH + ob) =
                        cvt4((acc[i][b][0] + b0) * L2E, (acc[i][b][1] + b1) * L2E,
                             (acc[i][b][2] + b2) * L2E, (acc[i][b][3] + b3) * L2E);
                }
            } else {                       // K -> Kt[n][o]
                unsigned short* Kp = Kt + (size_t)mi * NPIX * QCH;
                int o2 = ob - 32;
                float b0 = bk[o2], b1 = bk[o2 + 1], b2 = bk[o2 + 2], b3 = bk[o2 + 3];
#pragma unroll
                for (int b = 0; b < 4; ++b) {
                    int n = n0 + b * 16 + lj;
                    *(u16x4*)(Kp + (size_t)n * QCH + o2) =
                        cvt4(acc[i][b][0] + b0, acc[i][b][1] + b1,
                             acc[i][b][2] + b2, acc[i][b][3] + b3);
                }
            }
        } else {                           // V (swapped): thread = (c=c16*16+lj, n=n0+b*16+4q+r)
            unsigned short* Vw = V + (size_t)mi * SLICE;
            const int c16 = w + 4 * (i - 1);
            const float bb = bv[c16 * 16 + lj];
            const int n05 = n0 >> 5;
#pragma unroll
            for (int b = 0; b < 4; ++b) {
                const int l = lj | (((b & 1) * 2 + (q >> 1)) << 4);
                size_t base = ((size_t)(c16 * 32 + n05 + (b >> 1)) * 64 + l) * 8 + (q & 1) * 4;
                *(u16x4*)(Vw + base) = cvt4(acc[i][b][0] + bb, acc[i][b][1] + bb,
                                            acc[i][b][2] + bb, acc[i][b][3] + bb);
            }
        }
    }
}

// ---------------------------------------------------------------------------
// K2a (fallback only): row log-sums a2[n] = SHIFT + log2(sum_j 2^(e-SHIFT)).
// ---------------------------------------------------------------------------
__global__ __launch_bounds__(256) void k_stats(
    const unsigned short* __restrict__ Qt, const unsigned short* __restrict__ Kt,
    float* __restrict__ a2f)
{
    const int t = threadIdx.x, lane = t & 63, w = t >> 6;
    const int lj = lane & 15, q = lane >> 4;
    const int n16 = blockIdx.x * 64 + w * 16;
    const int mi = blockIdx.y;
    const unsigned short* Qp = Qt + (size_t)mi * NPIX * QCH;
    const unsigned short* Kp = Kt + (size_t)mi * NPIX * QCH;

    bf16x8 qa = ldfrag(Qp + (size_t)(n16 + lj) * QCH + q * 8);

    float s[4] = { 0.f, 0.f, 0.f, 0.f };
#pragma unroll 8
    for (int jc = 0; jc < NPIX; jc += 16) {
        bf16x8 kb = ldfrag(Kp + (size_t)(jc + lj) * QCH + q * 8);
        f32x4 z = (f32x4){0.f, 0.f, 0.f, 0.f};
        f32x4 e = __builtin_amdgcn_mfma_f32_16x16x32_bf16(qa, kb, z, 0, 0, 0);
#pragma unroll
        for (int r = 0; r < 4; ++r) s[r] += exp2f(e[r] - SHIFT);
    }
#pragma unroll
    for (int msk = 1; msk <= 8; msk <<= 1)
#pragma unroll
        for (int r = 0; r < 4; ++r) s[r] += __shfl_xor(s[r], msk, 64);
    if (lj == 0) {
        float* apo = a2f + (size_t)mi * NPIX;
#pragma unroll
        for (int r = 0; r < 4; ++r)
            apo[n16 + 4 * q + r] = SHIFT + log2f(s[r]);
    }
}

// ---------------------------------------------------------------------------
// K2b (primary, r11-verified): UNNORMALIZED Pu = exp2(e - SHIFT) as bf16
// B-frags, accumulating row sums S via shfl-reduce + atomicAdd.
// Grid (32, MB): n128 blocks x j-quarters (r7 = session-best config).
// ---------------------------------------------------------------------------
__global__ __launch_bounds__(256) void k_pu(
    const unsigned short* __restrict__ Qt, const unsigned short* __restrict__ Kt,
    float* __restrict__ S, unsigned short* __restrict__ Pu)
{
    __shared__ unsigned short Ps[4][32][36];   // wave-private [j32][n32], pitch 36

    const int t = threadIdx.x, lane = t & 63, w = t >> 6;
    const int lj = lane & 15, q = lane >> 4;
    const int nb = blockIdx.x >> 2;            // n128 block 0..7
    const int jh = blockIdx.x & 3;             // j-quarter 0..3
    const int nw = nb * 128 + w * 32;
    const int mi = blockIdx.y;
    const unsigned short* Qp = Qt + (size_t)mi * NPIX * QCH;
    const unsigned short* Kp = Kt + (size_t)mi * NPIX * QCH;
    unsigned short* Pup = Pu + (size_t)mi * NPIX * NPIX;

    bf16x8 qa[2];
#pragma unroll
    for (int h = 0; h < 2; ++h)
        qa[h] = ldfrag(Qp + (size_t)(nw + h * 16 + lj) * QCH + q * 8);

    float s[2][4];
#pragma unroll
    for (int h = 0; h < 2; ++h)
#pragma unroll
        for (int r = 0; r < 4; ++r) s[h][r] = 0.f;

    const int jbeg = jh * 256;
#pragma unroll 2
    for (int jc = jbeg; jc < jbeg + 256; jc += 32) {
#pragma unroll
        for (int f = 0; f < 2; ++f) {
            bf16x8 kb = ldfrag(Kp + (size_t)(jc + f * 16 + lj) * QCH + q * 8);
#pragma unroll
            for (int h = 0; h < 2; ++h) {
                f32x4 z = (f32x4){0.f, 0.f, 0.f, 0.f};
                f32x4 e = __builtin_amdgcn_mfma_f32_16x16x32_bf16(qa[h], kb, z, 0, 0, 0);
                float p0 = exp2f(e[0] - SHIFT), p1 = exp2f(e[1] - SHIFT);
                float p2 = exp2f(e[2] - SHIFT), p3 = exp2f(e[3] - SHIFT);
                s[h][0] += p0; s[h][1] += p1; s[h][2] += p2; s[h][3] += p3;
                *(u16x4*)&Ps[w][f * 16 + lj][h * 16 + 4 * q] = cvt4(p0, p1, p2, p3);
            }
        }
        // read back as B-frags (k=n32 x j16) and store to global frag layout
#pragma unroll
        for (int f = 0; f < 2; ++f) {
            u32x4 bfrag = *(const u32x4*)&Ps[w][f * 16 + lj][q * 8];
            *(u32x4*)(Pup + ((size_t)((jc >> 4) + f) * 32 + (nw >> 5)) * 512 + lane * 8) = bfrag;
        }
    }

    // row-sum reduce across the 16 j-lanes (lj), then one atomic per row
#pragma unroll
    for (int msk = 1; msk <= 8; msk <<= 1)
#pragma unroll
        for (int h = 0; h < 2; ++h)
#pragma unroll
            for (int r = 0; r < 4; ++r) s[h][r] += __shfl_xor(s[h][r], msk, 64);
    if (lj == 0) {
        float* Sp = S + (size_t)mi * NPIX;
#pragma unroll
        for (int h = 0; h < 2; ++h)
#pragma unroll
            for (int r = 0; r < 4; ++r)
                atomicAdd(&Sp[nw + h * 16 + 4 * q + r], s[h][r]);
    }
}

// ---------------------------------------------------------------------------
// K3 (primary, r11-verified): fragment GEMM O = (V/S) @ Pu_unnorm + residual.
// 1/S folded into V at LDS staging. cb4 grid 1024, Pu prefetch depth-2.
// ---------------------------------------------------------------------------
__global__ __launch_bounds__(256, 4) void k_gemm_out(
    const float* __restrict__ x, const float* __restrict__ gamma,
    const unsigned short* __restrict__ Vf, const unsigned short* __restrict__ Pu,
    const float* __restrict__ S, float* __restrict__ out)
{
    __shared__ unsigned short Vs[2][4096];   // dbuf: 2 chunks x 4 c-frags x 1KB
    __shared__ float rs[NPIX];               // 1/S_n for this mi (4 KB)

    const int b = blockIdx.x;                // 0..1023
    const int mi  = (b & 7) | ((b >> 8) << 3);
    const int sub = (b >> 3) & 31;
    const int j0  = (sub & 7) * 128;
    const int cb  = sub >> 3;                // 0..3 (64 channels each)

    const int t = threadIdx.x, lane = t & 63, w = t >> 6;
    const int lj = lane & 15, q = lane >> 4;
    const int jw = j0 + w * 32;

    const float* Sp = S + (size_t)mi * NPIX;
#pragma unroll
    for (int k = 0; k < 4; ++k)
        rs[t + k * 256] = 1.0f / Sp[t + k * 256];

    const unsigned short* Vp  = Vf + (size_t)mi * SLICE;
    const unsigned short* Pup = Pu + (size_t)mi * NPIX * NPIX
                              + ((size_t)(jw >> 4) * 32) * 512 + lane * 8;

    const int fs = t >> 5;                   // 0..7 = chunk-half (fs>>2) x c-frag (fs&3)
    const int ln0 = (t & 31) * 2;
    const int g8 = (ln0 >> 4) * 8;           // n_loc base for this thread's frag lanes
    const unsigned short* vsrc0 = Vp
        + ((size_t)((cb * 4 + (fs & 3)) * 32) + (fs >> 2)) * 512 + ln0 * 8;

    f32x4 acc[4][2];
#pragma unroll
    for (int ci = 0; ci < 4; ++ci)
#pragma unroll
        for (int f = 0; f < 2; ++f) acc[ci][f] = (f32x4){0.f, 0.f, 0.f, 0.f};

    __syncthreads();                         // rs ready

    // prestage pair 0 (chunks 0,1), scaled by 1/S
    {
        const float* r8 = &rs[(fs >> 2) * 32 + g8];
        u32x4 d0 = vscale(*(const u32x4*)vsrc0, r8);
        u32x4 d1 = vscale(*(const u32x4*)(vsrc0 + 8), r8);
        *(u32x4*)&Vs[0][fs * 512 + ln0 * 8] = d0;
        *(u32x4*)&Vs[0][fs * 512 + ln0 * 8 + 8] = d1;
    }
    bf16x8 pf[2][2], pfN[2][2];
#pragma unroll
    for (int h = 0; h < 2; ++h)
#pragma unroll
        for (int f = 0; f < 2; ++f) {
            pf[h][f]  = ldfrag(Pup + f * 16384 + (size_t)h * 512);
            pfN[h][f] = ldfrag(Pup + f * 16384 + (size_t)(2 + h) * 512);
        }
    __syncthreads();

    int p = 0;
    for (int nc = 0; nc < NPIX; nc += 64, p ^= 1) {
        const int n1 = (nc + 64) & (NPIX - 1);    // next pair (V staging)
        const int n2 = (nc + 128) & (NPIX - 1);   // pair+2 (Pu prefetch)
        const unsigned short* vs = vsrc0 + (size_t)(n1 >> 6) * 1024;
        u32x4 nv0 = *(const u32x4*)vs;
        u32x4 nv1 = *(const u32x4*)(vs + 8);
        bf16x8 pf2[2][2];
#pragma unroll
        for (int h = 0; h < 2; ++h)
#pragma unroll
            for (int f = 0; f < 2; ++f)
                pf2[h][f] = ldfrag(Pup + f * 16384 + ((size_t)(n2 >> 5) + h) * 512);

        // O phase: 16 MFMA
        __builtin_amdgcn_s_setprio(1);
#pragma unroll
        for (int h = 0; h < 2; ++h) {
#pragma unroll
            for (int ci = 0; ci < 4; ++ci) {
                bf16x8 vfr = ldfrag(&Vs[p][(h * 4 + ci) * 512 + lane * 8]);
#pragma unroll
                for (int f = 0; f < 2; ++f)
                    acc[ci][f] = __builtin_amdgcn_mfma_f32_16x16x32_bf16(vfr, pf[h][f], acc[ci][f], 0, 0, 0);
            }
        }
        __builtin_amdgcn_s_setprio(0);

        // scale next V pair by 1/S, then stage
        {
            const float* r8 = &rs[((n1 >> 5) + (fs >> 2)) * 32 + g8];
            nv0 = vscale(nv0, r8);
            nv1 = vscale(nv1, r8);
        }
        *(u32x4*)&Vs[p ^ 1][fs * 512 + ln0 * 8] = nv0;
        *(u32x4*)&Vs[p ^ 1][fs * 512 + ln0 * 8 + 8] = nv1;
        __syncthreads();
#pragma unroll
        for (int h = 0; h < 2; ++h)
#pragma unroll
            for (int f = 0; f < 2; ++f) { pf[h][f] = pfN[h][f]; pfN[h][f] = pf2[h][f]; }
    }

    const float g = gamma[0];
    const size_t obase = (size_t)mi * SLICE;
#pragma unroll
    for (int ci = 0; ci < 4; ++ci) {
#pragma unroll
        for (int f = 0; f < 2; ++f) {
#pragma unroll
            for (int r = 0; r < 4; ++r) {
                int c = cb * 64 + ci * 16 + 4 * q + r;
                int j = jw + f * 16 + lj;
                size_t off = obase + (size_t)c * NPIX + j;
                out[off] = g * acc[ci][f][r] + x[off];
            }
        }
    }
}

// ---------------------------------------------------------------------------
// Fallback K3 (r5-verified) for small ws_size: recompute E, exp2(e - a2).
// ---------------------------------------------------------------------------
__global__ __launch_bounds__(256) void k_attn_out(
    const float* __restrict__ x, const float* __restrict__ gamma,
    const unsigned short* __restrict__ Qt, const unsigned short* __restrict__ Kt,
    const unsigned short* __restrict__ Vf, const float* __restrict__ a2f,
    float* __restrict__ out)
{
    __shared__ unsigned short Vs[2][8 * 512];
    __shared__ unsigned short Ps[4][32][36];

    const int b = blockIdx.x;
    const int mi  = (b & 7) | ((b >> 7) << 3);
    const int sub = (b >> 3) & 15;
    const int j0  = (sub & 7) * 128;
    const int cb  = sub >> 3;

    const int t = threadIdx.x, lane = t & 63, w = t >> 6;
    const int lj = lane & 15, q = lane >> 4;
    const int jw = j0 + w * 32;

    const unsigned short* Qp = Qt + (size_t)mi * NPIX * QCH;
    const unsigned short* Kp = Kt + (size_t)mi * NPIX * QCH;
    const unsigned short* Vp = Vf + (size_t)mi * SLICE;
    const float* ap = a2f + (size_t)mi * NPIX;

    bf16x8 kb[2];
#pragma unroll
    for (int sj = 0; sj < 2; ++sj)
        kb[sj] = ldfrag(Kp + (size_t)(jw + sj * 16 + lj) * QCH + q * 8);

    const int ctl = t >> 5, ln0 = (t & 31) * 2;
    const unsigned short* vsrc0 = Vp + ((size_t)(cb * 8 + ctl) * 32) * 512 + ln0 * 8;

    f32x4 acc[8][2];
#pragma unroll
    for (int ci = 0; ci < 8; ++ci)
#pragma unroll
        for (int ji = 0; ji < 2; ++ji) acc[ci][ji] = (f32x4){0.f, 0.f, 0.f, 0.f};

    {
        u32x4 d0 = *(const u32x4*)vsrc0;
        u32x4 d1 = *(const u32x4*)(vsrc0 + 8);
        *(u32x4*)&Vs[0][ctl * 512 + ln0 * 8] = d0;
        *(u32x4*)&Vs[0][ctl * 512 + ln0 * 8 + 8] = d1;
    }
    bf16x8 qa_n[2];
    f32x4  a4_n[2];
#pragma unroll
    for (int sn = 0; sn < 2; ++sn) {
        qa_n[sn] = ldfrag(Qp + (size_t)(sn * 16 + lj) * QCH + q * 8);
        a4_n[sn] = *(const f32x4*)(ap + sn * 16 + 4 * q);
    }
    __syncthreads();

    int p = 0;
    for (int nc = 0; nc < NPIX; nc += 32, p ^= 1) {
        const int nn = (nc + 32) & (NPIX - 1);
        const unsigned short* vsrc = vsrc0 + (size_t)(nn >> 5) * 512;
        u32x4 nv0 = *(const u32x4*)vsrc;
        u32x4 nv1 = *(const u32x4*)(vsrc + 8);

        bf16x8 qa0 = qa_n[0], qa1 = qa_n[1];
        f32x4 a40 = a4_n[0], a41 = a4_n[1];
#pragma unroll
        for (int sj = 0; sj < 2; ++sj) {
            f32x4 z = (f32x4){0.f, 0.f, 0.f, 0.f};
            f32x4 e0 = __builtin_amdgcn_mfma_f32_16x16x32_bf16(qa0, kb[sj], z, 0, 0, 0);
            f32x4 e1 = __builtin_amdgcn_mfma_f32_16x16x32_bf16(qa1, kb[sj], z, 0, 0, 0);
            *(u16x4*)&Ps[w][sj * 16 + lj][4 * q] =
                cvt4(exp2f(e0[0] - a40[0]), exp2f(e0[1] - a40[1]),
                     exp2f(e0[2] - a40[2]), exp2f(e0[3] - a40[3]));
            *(u16x4*)&Ps[w][sj * 16 + lj][16 + 4 * q] =
                cvt4(exp2f(e1[0] - a41[0]), exp2f(e1[1] - a41[1]),
                     exp2f(e1[2] - a41[2]), exp2f(e1[3] - a41[3]));
        }
#pragma unroll
        for (int sn = 0; sn < 2; ++sn) {
            qa_n[sn] = ldfrag(Qp + (size_t)(nn + sn * 16 + lj) * QCH + q * 8);
            a4_n[sn] = *(const f32x4*)(ap + nn + sn * 16 + 4 * q);
        }

        bf16x8 pf[2];
#pragma unroll
        for (int ji = 0; ji < 2; ++ji)
            pf[ji] = ldfrag(&Ps[w][ji * 16 + lj][q * 8]);
#pragma unroll
        for (int ci = 0; ci < 8; ++ci) {
            bf16x8 vfr = ldfrag(&Vs[p][ci * 512 + lane * 8]);
#pragma unroll
            for (int ji = 0; ji < 2; ++ji)
                acc[ci][ji] = __builtin_amdgcn_mfma_f32_16x16x32_bf16(vfr, pf[ji], acc[ci][ji], 0, 0, 0);
        }

        *(u32x4*)&Vs[p ^ 1][ctl * 512 + ln0 * 8] = nv0;
        *(u32x4*)&Vs[p ^ 1][ctl * 512 + ln0 * 8 + 8] = nv1;
        __syncthreads();
    }

    const float g = gamma[0];
    const size_t obase = (size_t)mi * SLICE;
#pragma unroll
    for (int ci = 0; ci < 8; ++ci) {
#pragma unroll
        for (int ji = 0; ji < 2; ++ji) {
#pragma unroll
            for (int r = 0; r < 4; ++r) {
                int c = cb * 128 + ci * 16 + 4 * q + r;
                int j = jw + ji * 16 + lj;
                size_t off = obase + (size_t)c * NPIX + j;
                out[off] = g * acc[ci][ji][r] + x[off];
            }
        }
    }
}

extern "C" void kernel_launch(void* const* d_in, const int* in_sizes, int n_in,
                              void* d_out, int out_size, void* d_ws, size_t ws_size,
                              hipStream_t stream)
{
    const float* x     = (const float*)d_in[0];
    const float* wq    = (const float*)d_in[1];
    const float* bq    = (const float*)d_in[2];
    const float* wk    = (const float*)d_in[3];
    const float* bk    = (const float*)d_in[4];
    const float* wv    = (const float*)d_in[5];
    const float* bv    = (const float*)d_in[6];
    const float* gamma = (const float*)d_in[7];
    float* out = (float*)d_out;

    char* wsb = (char*)d_ws;
    unsigned short* Wb = (unsigned short*)(wsb + WB_OFF);
    unsigned short* Qt = (unsigned short*)(wsb + QT_OFF);
    unsigned short* Kt = (unsigned short*)(wsb + KT_OFF);
    unsigned short* V  = (unsigned short*)(wsb + V_OFF);
    float*          Sa = (float*)(wsb + A2F_OFF);   // primary: sums; fallback: log-sums
    unsigned short* Pu = (unsigned short*)(wsb + PU_OFF);

    k_prep_w<<<128, 256, 0, stream>>>(wq, wk, wv, Wb, Sa);
    k_proj<<<dim3(NPIX / 64, MB), 256, 0, stream>>>(x, Wb, bq, bk, bv, Qt, Kt, V);

    if (ws_size >= (size_t)WS_NEED) {
        k_pu<<<dim3(32, MB), 256, 0, stream>>>(Qt, Kt, Sa, Pu);
        k_gemm_out<<<1024, 256, 0, stream>>>(x, gamma, V, Pu, Sa, out);
    } else {
        k_stats<<<dim3(NPIX / 64, MB), 256, 0, stream>>>(Qt, Kt, Sa);
        k_attn_out<<<512, 256, 0, stream>>>(x, gamma, Qt, Kt, V, Sa, out);
    }
}

// Round 13
// 148.211 us; speedup vs baseline: 1.1259x; 1.0312x over previous
//
#include <hip/hip_runtime.h>

#define MB    32        // B*T slices
#define CCH   256       // channels C
#define QCH   32        // q/k channels
#define NPIX  1024      // W*H
#define SLICE (CCH * NPIX)   // 262144
#define L2E   1.44269504088896340736f
#define SHIFT 32.0f     // fixed softmax shift (log2-domain energies well within fp32 range)

typedef __bf16          bf16x8 __attribute__((ext_vector_type(8)));
typedef __bf16          bf16x4 __attribute__((ext_vector_type(4)));
typedef float           f32x4  __attribute__((ext_vector_type(4)));
typedef unsigned int    u32x4  __attribute__((ext_vector_type(4)));
typedef unsigned short  u16x4  __attribute__((ext_vector_type(4)));

#define XP 270          // Xs pitch (u16): 135 dw == 7 mod 32 -> 2-way (free) stage writes

__device__ __forceinline__ unsigned short f2bf(float f) {
    unsigned int u = __builtin_bit_cast(unsigned int, f);
    u += 0x7FFFu + ((u >> 16) & 1u);          // RTNE
    return (unsigned short)(u >> 16);
}
__device__ __forceinline__ u16x4 cvt4(float a, float b, float c, float d) {
    bf16x4 v = { (__bf16)a, (__bf16)b, (__bf16)c, (__bf16)d };   // v_cvt_pk_bf16_f32
    return __builtin_bit_cast(u16x4, v);
}
__device__ __forceinline__ float bf2f(unsigned short u) {
    unsigned int v = (unsigned int)u << 16;
    return __builtin_bit_cast(float, v);
}
__device__ __forceinline__ bf16x8 ldfrag(const unsigned short* p) {
    u32x4 u = *(const u32x4*)p;
    return __builtin_bit_cast(bf16x8, u);
}
// scale 8 bf16 (one V-frag lane) by r8[0..7], repack (RTNE)
__device__ __forceinline__ u32x4 vscale(u32x4 d, const float* __restrict__ r8) {
    const unsigned short* ds = (const unsigned short*)&d;
    u16x4 a = cvt4(bf2f(ds[0]) * r8[0], bf2f(ds[1]) * r8[1],
                   bf2f(ds[2]) * r8[2], bf2f(ds[3]) * r8[3]);
    u16x4 b = cvt4(bf2f(ds[4]) * r8[4], bf2f(ds[5]) * r8[5],
                   bf2f(ds[6]) * r8[6], bf2f(ds[7]) * r8[7]);
    u32x4 o;
    ((u16x4*)&o)[0] = a;
    ((u16x4*)&o)[1] = b;
    return o;
}

// workspace byte offsets
#define WB_OFF  0u              // 320*256 bf16 = 163840
#define QT_OFF  262144u         // 2 MB
#define KT_OFF  2359296u        // 2 MB
#define V_OFF   4456448u        // 16 MB (MFMA A-frag layout)
#define A2F_OFF 21233664u       // 128 KB: primary = row sums S (f32); fallback = log-sums a2f
#define PU_OFF  21364736u       // 64 MB (primary path only: UNNORMALIZED Pu B-frags)
#define WS_NEED 88473600u

// ---------------------------------------------------------------------------
// K0w (r11-verified): convert stacked [wq;wk;wv] (320x256 f32) -> Wb bf16,
// AND zero the row-sum buffer S[MB*NPIX] (32768 f32). Grid 128x256.
// ---------------------------------------------------------------------------
__global__ __launch_bounds__(256) void k_prep_w(
    const float* __restrict__ wq, const float* __restrict__ wk,
    const float* __restrict__ wv, unsigned short* __restrict__ Wb,
    float* __restrict__ S)
{
    int tid = blockIdx.x * 256 + threadIdx.x;
    S[tid] = 0.0f;
    int i4 = tid * 4;
    if (i4 < 320 * CCH) {
        int o = i4 >> 8, c = i4 & 255;
        const float* src = (o < 32) ? wq + (size_t)o * CCH + c
                         : (o < 64) ? wk + (size_t)(o - 32) * CCH + c
                                    : wv + (size_t)(o - 64) * CCH + c;
        float4 v = *(const float4*)src;
        *(u16x4*)(Wb + i4) = cvt4(v.x, v.y, v.z, v.w);
    }
}

// ---------------------------------------------------------------------------
// K1 (r16-verified): MFMA projections, fused x transpose+cvt, K-loop
// register double-buffered (hides L2/LDS latency at 2 waves/SIMD).
// ---------------------------------------------------------------------------
__global__ __launch_bounds__(256) void k_proj(
    const float* __restrict__ x, const unsigned short* __restrict__ Wb,
    const float* __restrict__ bq, const float* __restrict__ bk,
    const float* __restrict__ bv,
    unsigned short* __restrict__ Qt, unsigned short* __restrict__ Kt,
    unsigned short* __restrict__ V)
{
    __shared__ unsigned short Xs[64 * XP];    // [n][k256], pitch XP=270

    const int t = threadIdx.x, lane = t & 63, w = t >> 6;
    const int lj = lane & 15, q = lane >> 4;
    const int n0 = blockIdx.x * 64;
    const int mi = blockIdx.y;
    const float* xp = x + (size_t)mi * SLICE;

    // stage + transpose + cvt (c-pairs -> packed u32 LDS writes)
#pragma unroll
    for (int r = 0; r < 8; ++r) {
        int job = t + r * 256;          // 0..2047
        int cp = job >> 4;              // c-pair 0..127
        int seg = job & 15;             // 4-wide n segment
        float4 va = *(const float4*)(xp + (size_t)(2 * cp) * NPIX + n0 + seg * 4);
        float4 vb = *(const float4*)(xp + (size_t)(2 * cp + 1) * NPIX + n0 + seg * 4);
        u16x4 da = cvt4(va.x, va.y, va.z, va.w);
        u16x4 db = cvt4(vb.x, vb.y, vb.z, vb.w);
#pragma unroll
        for (int e = 0; e < 4; ++e) {
            unsigned pk = (unsigned)da[e] | ((unsigned)db[e] << 16);
            *(unsigned*)&Xs[(seg * 4 + e) * XP + 2 * cp] = pk;
        }
    }
    __syncthreads();

    f32x4 acc[5][4];
#pragma unroll
    for (int i = 0; i < 5; ++i)
#pragma unroll
        for (int b = 0; b < 4; ++b) acc[i][b] = (f32x4){0.f, 0.f, 0.f, 0.f};

    const unsigned short* wbase = Wb + (size_t)(w * 16 + lj) * CCH + q * 8;
    const unsigned short* xbase = &Xs[lj * XP + q * 8];

    // preload kc = 0 fragments
    bf16x8 a0[5], xb0[4];
#pragma unroll
    for (int i = 0; i < 5; ++i)
        a0[i] = ldfrag(wbase + (size_t)i * 64 * CCH);
#pragma unroll
    for (int b = 0; b < 4; ++b)
        xb0[b] = ldfrag(xbase + b * 16 * XP);

#pragma unroll
    for (int kc = 0; kc < CCH; kc += 32) {
        bf16x8 a1[5], xb1[4];
        if (kc + 32 < CCH) {            // compile-time per unrolled iter
#pragma unroll
            for (int i = 0; i < 5; ++i)
                a1[i] = ldfrag(wbase + (size_t)i * 64 * CCH + kc + 32);
#pragma unroll
            for (int b = 0; b < 4; ++b)
                xb1[b] = ldfrag(xbase + b * 16 * XP + kc + 32);
        }
#pragma unroll
        for (int i = 0; i < 5; ++i)
#pragma unroll
            for (int b = 0; b < 4; ++b)
                acc[i][b] = (i == 0)
                    ? __builtin_amdgcn_mfma_f32_16x16x32_bf16(a0[i], xb0[b], acc[i][b], 0, 0, 0)
                    : __builtin_amdgcn_mfma_f32_16x16x32_bf16(xb0[b], a0[i], acc[i][b], 0, 0, 0);
        if (kc + 32 < CCH) {
#pragma unroll
            for (int i = 0; i < 5; ++i) a0[i] = a1[i];
#pragma unroll
            for (int b = 0; b < 4; ++b) xb0[b] = xb1[b];
        }
    }

#pragma unroll
    for (int i = 0; i < 5; ++i) {
        if (i == 0) {
            const int ob = w * 16 + 4 * q;
            if (w < 2) {                   // Q -> Qt[n][o], pre-scaled by log2(e)
                unsigned short* Qp = Qt + (size_t)mi * NPIX * QCH;
                float b0 = bq[ob], b1 = bq[ob + 1], b2 = bq[ob + 2], b3 = bq[ob + 3];
#pragma unroll
                for (int b = 0; b < 4; ++b) {
                    int n = n0 + b * 16 + lj;
                    *(u16x4*)(Qp + (size_t)n * QCH + ob) =
                        cvt4((acc[i][b][0] + b0) * L2E, (acc[i][b][1] + b1) * L2E,
                             (acc[i][b][2] + b2) * L2E, (acc[i][b][3] + b3) * L2E);
                }
            } else {                       // K -> Kt[n][o]
                unsigned short* Kp = Kt + (size_t)mi * NPIX * QCH;
                int o2 = ob - 32;
                float b0 = bk[o2], b1 = bk[o2 + 1], b2 = bk[o2 + 2], b3 = bk[o2 + 3];
#pragma unroll
                for (int b = 0; b < 4; ++b) {
                    int n = n0 + b * 16 + lj;
                    *(u16x4*)(Kp + (size_t)n * QCH + o2) =
                        cvt4(acc[i][b][0] + b0, acc[i][b][1] + b1,
                             acc[i][b][2] + b2, acc[i][b][3] + b3);
                }
            }
        } else {                           // V (swapped): thread = (c=c16*16+lj, n=n0+b*16+4q+r)
            unsigned short* Vw = V + (size_t)mi * SLICE;
            const int c16 = w + 4 * (i - 1);
            const float bb = bv[c16 * 16 + lj];
            const int n05 = n0 >> 5;
#pragma unroll
            for (int b = 0; b < 4; ++b) {
                const int l = lj | (((b & 1) * 2 + (q >> 1)) << 4);
                size_t base = ((size_t)(c16 * 32 + n05 + (b >> 1)) * 64 + l) * 8 + (q & 1) * 4;
                *(u16x4*)(Vw + base) = cvt4(acc[i][b][0] + bb, acc[i][b][1] + bb,
                                            acc[i][b][2] + bb, acc[i][b][3] + bb);
            }
        }
    }
}

// ---------------------------------------------------------------------------
// K2a (fallback only): row log-sums a2[n] = SHIFT + log2(sum_j 2^(e-SHIFT)).
// ---------------------------------------------------------------------------
__global__ __launch_bounds__(256) void k_stats(
    const unsigned short* __restrict__ Qt, const unsigned short* __restrict__ Kt,
    float* __restrict__ a2f)
{
    const int t = threadIdx.x, lane = t & 63, w = t >> 6;
    const int lj = lane & 15, q = lane >> 4;
    const int n16 = blockIdx.x * 64 + w * 16;
    const int mi = blockIdx.y;
    const unsigned short* Qp = Qt + (size_t)mi * NPIX * QCH;
    const unsigned short* Kp = Kt + (size_t)mi * NPIX * QCH;

    bf16x8 qa = ldfrag(Qp + (size_t)(n16 + lj) * QCH + q * 8);

    float s[4] = { 0.f, 0.f, 0.f, 0.f };
#pragma unroll 8
    for (int jc = 0; jc < NPIX; jc += 16) {
        bf16x8 kb = ldfrag(Kp + (size_t)(jc + lj) * QCH + q * 8);
        f32x4 z = (f32x4){0.f, 0.f, 0.f, 0.f};
        f32x4 e = __builtin_amdgcn_mfma_f32_16x16x32_bf16(qa, kb, z, 0, 0, 0);
#pragma unroll
        for (int r = 0; r < 4; ++r) s[r] += exp2f(e[r] - SHIFT);
    }
#pragma unroll
    for (int msk = 1; msk <= 8; msk <<= 1)
#pragma unroll
        for (int r = 0; r < 4; ++r) s[r] += __shfl_xor(s[r], msk, 64);
    if (lj == 0) {
        float* apo = a2f + (size_t)mi * NPIX;
#pragma unroll
        for (int r = 0; r < 4; ++r)
            apo[n16 + 4 * q + r] = SHIFT + log2f(s[r]);
    }
}

// ---------------------------------------------------------------------------
// K2b (primary, r17): UNNORMALIZED Pu = exp2(e - SHIFT) as bf16 B-frags,
// accumulating row sums S via shfl-reduce + atomicAdd. Grid (32, MB).
// r17: K-frag register prefetch (r16's verified technique applied here) —
// next iteration's 2 kb frags issue before this iteration's MFMA/exp2/LDS
// chain; wraparound index avoids the tail branch. +8 VGPR, no dup work.
// ---------------------------------------------------------------------------
__global__ __launch_bounds__(256) void k_pu(
    const unsigned short* __restrict__ Qt, const unsigned short* __restrict__ Kt,
    float* __restrict__ S, unsigned short* __restrict__ Pu)
{
    __shared__ unsigned short Ps[4][32][36];   // wave-private [j32][n32], pitch 36

    const int t = threadIdx.x, lane = t & 63, w = t >> 6;
    const int lj = lane & 15, q = lane >> 4;
    const int nb = blockIdx.x >> 2;            // n128 block 0..7
    const int jh = blockIdx.x & 3;             // j-quarter 0..3
    const int nw = nb * 128 + w * 32;
    const int mi = blockIdx.y;
    const unsigned short* Qp = Qt + (size_t)mi * NPIX * QCH;
    const unsigned short* Kp = Kt + (size_t)mi * NPIX * QCH;
    unsigned short* Pup = Pu + (size_t)mi * NPIX * NPIX;

    bf16x8 qa[2];
#pragma unroll
    for (int h = 0; h < 2; ++h)
        qa[h] = ldfrag(Qp + (size_t)(nw + h * 16 + lj) * QCH + q * 8);

    float s[2][4];
#pragma unroll
    for (int h = 0; h < 2; ++h)
#pragma unroll
        for (int r = 0; r < 4; ++r) s[h][r] = 0.f;

    const int jbeg = jh * 256;
    // preload first iteration's K frags
    bf16x8 kb0 = ldfrag(Kp + (size_t)(jbeg + lj) * QCH + q * 8);
    bf16x8 kb1 = ldfrag(Kp + (size_t)(jbeg + 16 + lj) * QCH + q * 8);

#pragma unroll 2
    for (int j0 = 0; j0 < 256; j0 += 32) {
        const int jc = jbeg + j0;
        const int jn = jbeg + ((j0 + 32) & 255);   // wraparound: always valid
        bf16x8 nk0 = ldfrag(Kp + (size_t)(jn + lj) * QCH + q * 8);
        bf16x8 nk1 = ldfrag(Kp + (size_t)(jn + 16 + lj) * QCH + q * 8);

#pragma unroll
        for (int f = 0; f < 2; ++f) {
            bf16x8 kb = (f == 0) ? kb0 : kb1;
#pragma unroll
            for (int h = 0; h < 2; ++h) {
                f32x4 z = (f32x4){0.f, 0.f, 0.f, 0.f};
                f32x4 e = __builtin_amdgcn_mfma_f32_16x16x32_bf16(qa[h], kb, z, 0, 0, 0);
                float p0 = exp2f(e[0] - SHIFT), p1 = exp2f(e[1] - SHIFT);
                float p2 = exp2f(e[2] - SHIFT), p3 = exp2f(e[3] - SHIFT);
                s[h][0] += p0; s[h][1] += p1; s[h][2] += p2; s[h][3] += p3;
                *(u16x4*)&Ps[w][f * 16 + lj][h * 16 + 4 * q] = cvt4(p0, p1, p2, p3);
            }
        }
        // read back as B-frags (k=n32 x j16) and store to global frag layout
#pragma unroll
        for (int f = 0; f < 2; ++f) {
            u32x4 bfrag = *(const u32x4*)&Ps[w][f * 16 + lj][q * 8];
            *(u32x4*)(Pup + ((size_t)((jc >> 4) + f) * 32 + (nw >> 5)) * 512 + lane * 8) = bfrag;
        }
        kb0 = nk0; kb1 = nk1;
    }

    // row-sum reduce across the 16 j-lanes (lj), then one atomic per row
#pragma unroll
    for (int msk = 1; msk <= 8; msk <<= 1)
#pragma unroll
        for (int h = 0; h < 2; ++h)
#pragma unroll
            for (int r = 0; r < 4; ++r) s[h][r] += __shfl_xor(s[h][r], msk, 64);
    if (lj == 0) {
        float* Sp = S + (size_t)mi * NPIX;
#pragma unroll
        for (int h = 0; h < 2; ++h)
#pragma unroll
            for (int r = 0; r < 4; ++r)
                atomicAdd(&Sp[nw + h * 16 + 4 * q + r], s[h][r]);
    }
}

// ---------------------------------------------------------------------------
// K3 (primary, r11-verified): fragment GEMM O = (V/S) @ Pu_unnorm + residual.
// 1/S folded into V at LDS staging. cb4 grid 1024, Pu prefetch depth-2.
// ---------------------------------------------------------------------------
__global__ __launch_bounds__(256, 4) void k_gemm_out(
    const float* __restrict__ x, const float* __restrict__ gamma,
    const unsigned short* __restrict__ Vf, const unsigned short* __restrict__ Pu,
    const float* __restrict__ S, float* __restrict__ out)
{
    __shared__ unsigned short Vs[2][4096];   // dbuf: 2 chunks x 4 c-frags x 1KB
    __shared__ float rs[NPIX];               // 1/S_n for this mi (4 KB)

    const int b = blockIdx.x;                // 0..1023
    const int mi  = (b & 7) | ((b >> 8) << 3);
    const int sub = (b >> 3) & 31;
    const int j0  = (sub & 7) * 128;
    const int cb  = sub >> 3;                // 0..3 (64 channels each)

    const int t = threadIdx.x, lane = t & 63, w = t >> 6;
    const int lj = lane & 15, q = lane >> 4;
    const int jw = j0 + w * 32;

    const float* Sp = S + (size_t)mi * NPIX;
#pragma unroll
    for (int k = 0; k < 4; ++k)
        rs[t + k * 256] = 1.0f / Sp[t + k * 256];

    const unsigned short* Vp  = Vf + (size_t)mi * SLICE;
    const unsigned short* Pup = Pu + (size_t)mi * NPIX * NPIX
                              + ((size_t)(jw >> 4) * 32) * 512 + lane * 8;

    const int fs = t >> 5;                   // 0..7 = chunk-half (fs>>2) x c-frag (fs&3)
    const int ln0 = (t & 31) * 2;
    const int g8 = (ln0 >> 4) * 8;           // n_loc base for this thread's frag lanes
    const unsigned short* vsrc0 = Vp
        + ((size_t)((cb * 4 + (fs & 3)) * 32) + (fs >> 2)) * 512 + ln0 * 8;

    f32x4 acc[4][2];
#pragma unroll
    for (int ci = 0; ci < 4; ++ci)
#pragma unroll
        for (int f = 0; f < 2; ++f) acc[ci][f] = (f32x4){0.f, 0.f, 0.f, 0.f};

    __syncthreads();                         // rs ready

    // prestage pair 0 (chunks 0,1), scaled by 1/S
    {
        const float* r8 = &rs[(fs >> 2) * 32 + g8];
        u32x4 d0 = vscale(*(const u32x4*)vsrc0, r8);
        u32x4 d1 = vscale(*(const u32x4*)(vsrc0 + 8), r8);
        *(u32x4*)&Vs[0][fs * 512 + ln0 * 8] = d0;
        *(u32x4*)&Vs[0][fs * 512 + ln0 * 8 + 8] = d1;
    }
    bf16x8 pf[2][2], pfN[2][2];
#pragma unroll
    for (int h = 0; h < 2; ++h)
#pragma unroll
        for (int f = 0; f < 2; ++f) {
            pf[h][f]  = ldfrag(Pup + f * 16384 + (size_t)h * 512);
            pfN[h][f] = ldfrag(Pup + f * 16384 + (size_t)(2 + h) * 512);
        }
    __syncthreads();

    int p = 0;
    for (int nc = 0; nc < NPIX; nc += 64, p ^= 1) {
        const int n1 = (nc + 64) & (NPIX - 1);    // next pair (V staging)
        const int n2 = (nc + 128) & (NPIX - 1);   // pair+2 (Pu prefetch)
        const unsigned short* vs = vsrc0 + (size_t)(n1 >> 6) * 1024;
        u32x4 nv0 = *(const u32x4*)vs;
        u32x4 nv1 = *(const u32x4*)(vs + 8);
        bf16x8 pf2[2][2];
#pragma unroll
        for (int h = 0; h < 2; ++h)
#pragma unroll
            for (int f = 0; f < 2; ++f)
                pf2[h][f] = ldfrag(Pup + f * 16384 + ((size_t)(n2 >> 5) + h) * 512);

        // O phase: 16 MFMA
        __builtin_amdgcn_s_setprio(1);
#pragma unroll
        for (int h = 0; h < 2; ++h) {
#pragma unroll
            for (int ci = 0; ci < 4; ++ci) {
                bf16x8 vfr = ldfrag(&Vs[p][(h * 4 + ci) * 512 + lane * 8]);
#pragma unroll
                for (int f = 0; f < 2; ++f)
                    acc[ci][f] = __builtin_amdgcn_mfma_f32_16x16x32_bf16(vfr, pf[h][f], acc[ci][f], 0, 0, 0);
            }
        }
        __builtin_amdgcn_s_setprio(0);

        // scale next V pair by 1/S, then stage
        {
            const float* r8 = &rs[((n1 >> 5) + (fs >> 2)) * 32 + g8];
            nv0 = vscale(nv0, r8);
            nv1 = vscale(nv1, r8);
        }
        *(u32x4*)&Vs[p ^ 1][fs * 512 + ln0 * 8] = nv0;
        *(u32x4*)&Vs[p ^ 1][fs * 512 + ln0 * 8 + 8] = nv1;
        __syncthreads();
#pragma unroll
        for (int h = 0; h < 2; ++h)
#pragma unroll
            for (int f = 0; f < 2; ++f) { pf[h][f] = pfN[h][f]; pfN[h][f] = pf2[h][f]; }
    }

    const float g = gamma[0];
    const size_t obase = (size_t)mi * SLICE;
#pragma unroll
    for (int ci = 0; ci < 4; ++ci) {
#pragma unroll
        for (int f = 0; f < 2; ++f) {
#pragma unroll
            for (int r = 0; r < 4; ++r) {
                int c = cb * 64 + ci * 16 + 4 * q + r;
                int j = jw + f * 16 + lj;
                size_t off = obase + (size_t)c * NPIX + j;
                out[off] = g * acc[ci][f][r] + x[off];
            }
        }
    }
}

// ---------------------------------------------------------------------------
// Fallback K3 (r5-verified) for small ws_size: recompute E, exp2(e - a2).
// ---------------------------------------------------------------------------
__global__ __launch_bounds__(256) void k_attn_out(
    const float* __restrict__ x, const float* __restrict__ gamma,
    const unsigned short* __restrict__ Qt, const unsigned short* __restrict__ Kt,
    const unsigned short* __restrict__ Vf, const float* __restrict__ a2f,
    float* __restrict__ out)
{
    __shared__ unsigned short Vs[2][8 * 512];
    __shared__ unsigned short Ps[4][32][36];

    const int b = blockIdx.x;
    const int mi  = (b & 7) | ((b >> 7) << 3);
    const int sub = (b >> 3) & 15;
    const int j0  = (sub & 7) * 128;
    const int cb  = sub >> 3;

    const int t = threadIdx.x, lane = t & 63, w = t >> 6;
    const int lj = lane & 15, q = lane >> 4;
    const int jw = j0 + w * 32;

    const unsigned short* Qp = Qt + (size_t)mi * NPIX * QCH;
    const unsigned short* Kp = Kt + (size_t)mi * NPIX * QCH;
    const unsigned short* Vp = Vf + (size_t)mi * SLICE;
    const float* ap = a2f + (size_t)mi * NPIX;

    bf16x8 kb[2];
#pragma unroll
    for (int sj = 0; sj < 2; ++sj)
        kb[sj] = ldfrag(Kp + (size_t)(jw + sj * 16 + lj) * QCH + q * 8);

    const int ctl = t >> 5, ln0 = (t & 31) * 2;
    const unsigned short* vsrc0 = Vp + ((size_t)(cb * 8 + ctl) * 32) * 512 + ln0 * 8;

    f32x4 acc[8][2];
#pragma unroll
    for (int ci = 0; ci < 8; ++ci)
#pragma unroll
        for (int ji = 0; ji < 2; ++ji) acc[ci][ji] = (f32x4){0.f, 0.f, 0.f, 0.f};

    {
        u32x4 d0 = *(const u32x4*)vsrc0;
        u32x4 d1 = *(const u32x4*)(vsrc0 + 8);
        *(u32x4*)&Vs[0][ctl * 512 + ln0 * 8] = d0;
        *(u32x4*)&Vs[0][ctl * 512 + ln0 * 8 + 8] = d1;
    }
    bf16x8 qa_n[2];
    f32x4  a4_n[2];
#pragma unroll
    for (int sn = 0; sn < 2; ++sn) {
        qa_n[sn] = ldfrag(Qp + (size_t)(sn * 16 + lj) * QCH + q * 8);
        a4_n[sn] = *(const f32x4*)(ap + sn * 16 + 4 * q);
    }
    __syncthreads();

    int p = 0;
    for (int nc = 0; nc < NPIX; nc += 32, p ^= 1) {
        const int nn = (nc + 32) & (NPIX - 1);
        const unsigned short* vsrc = vsrc0 + (size_t)(nn >> 5) * 512;
        u32x4 nv0 = *(const u32x4*)vsrc;
        u32x4 nv1 = *(const u32x4*)(vsrc + 8);

        bf16x8 qa0 = qa_n[0], qa1 = qa_n[1];
        f32x4 a40 = a4_n[0], a41 = a4_n[1];
#pragma unroll
        for (int sj = 0; sj < 2; ++sj) {
            f32x4 z = (f32x4){0.f, 0.f, 0.f, 0.f};
            f32x4 e0 = __builtin_amdgcn_mfma_f32_16x16x32_bf16(qa0, kb[sj], z, 0, 0, 0);
            f32x4 e1 = __builtin_amdgcn_mfma_f32_16x16x32_bf16(qa1, kb[sj], z, 0, 0, 0);
            *(u16x4*)&Ps[w][sj * 16 + lj][4 * q] =
                cvt4(exp2f(e0[0] - a40[0]), exp2f(e0[1] - a40[1]),
                     exp2f(e0[2] - a40[2]), exp2f(e0[3] - a40[3]));
            *(u16x4*)&Ps[w][sj * 16 + lj][16 + 4 * q] =
                cvt4(exp2f(e1[0] - a41[0]), exp2f(e1[1] - a41[1]),
                     exp2f(e1[2] - a41[2]), exp2f(e1[3] - a41[3]));
        }
#pragma unroll
        for (int sn = 0; sn < 2; ++sn) {
            qa_n[sn] = ldfrag(Qp + (size_t)(nn + sn * 16 + lj) * QCH + q * 8);
            a4_n[sn] = *(const f32x4*)(ap + nn + sn * 16 + 4 * q);
        }

        bf16x8 pf[2];
#pragma unroll
        for (int ji = 0; ji < 2; ++ji)
            pf[ji] = ldfrag(&Ps[w][ji * 16 + lj][q * 8]);
#pragma unroll
        for (int ci = 0; ci < 8; ++ci) {
            bf16x8 vfr = ldfrag(&Vs[p][ci * 512 + lane * 8]);
#pragma unroll
            for (int ji = 0; ji < 2; ++ji)
                acc[ci][ji] = __builtin_amdgcn_mfma_f32_16x16x32_bf16(vfr, pf[ji], acc[ci][ji], 0, 0, 0);
        }

        *(u32x4*)&Vs[p ^ 1][ctl * 512 + ln0 * 8] = nv0;
        *(u32x4*)&Vs[p ^ 1][ctl * 512 + ln0 * 8 + 8] = nv1;
        __syncthreads();
    }

    const float g = gamma[0];
    const size_t obase = (size_t)mi * SLICE;
#pragma unroll
    for (int ci = 0; ci < 8; ++ci) {
#pragma unroll
        for (int ji = 0; ji < 2; ++ji) {
#pragma unroll
            for (int r = 0; r < 4; ++r) {
                int c = cb * 128 + ci * 16 + 4 * q + r;
                int j = jw + ji * 16 + lj;
                size_t off = obase + (size_t)c * NPIX + j;
                out[off] = g * acc[ci][ji][r] + x[off];
            }
        }
    }
}

extern "C" void kernel_launch(void* const* d_in, const int* in_sizes, int n_in,
                              void* d_out, int out_size, void* d_ws, size_t ws_size,
                              hipStream_t stream)
{
    const float* x     = (const float*)d_in[0];
    const float* wq    = (const float*)d_in[1];
    const float* bq    = (const float*)d_in[2];
    const float* wk    = (const float*)d_in[3];
    const float* bk    = (const float*)d_in[4];
    const float* wv    = (const float*)d_in[5];
    const float* bv    = (const float*)d_in[6];
    const float* gamma = (const float*)d_in[7];
    float* out = (float*)d_out;

    char* wsb = (char*)d_ws;
    unsigned short* Wb = (unsigned short*)(wsb + WB_OFF);
    unsigned short* Qt = (unsigned short*)(wsb + QT_OFF);
    unsigned short* Kt = (unsigned short*)(wsb + KT_OFF);
    unsigned short* V  = (unsigned short*)(wsb + V_OFF);
    float*          Sa = (float*)(wsb + A2F_OFF);   // primary: sums; fallback: log-sums
    unsigned short* Pu = (unsigned short*)(wsb + PU_OFF);

    k_prep_w<<<128, 256, 0, stream>>>(wq, wk, wv, Wb, Sa);
    k_proj<<<dim3(NPIX / 64, MB), 256, 0, stream>>>(x, Wb, bq, bk, bv, Qt, Kt, V);

    if (ws_size >= (size_t)WS_NEED) {
        k_pu<<<dim3(32, MB), 256, 0, stream>>>(Qt, Kt, Sa, Pu);
        k_gemm_out<<<1024, 256, 0, stream>>>(x, gamma, V, Pu, Sa, out);
    } else {
        k_stats<<<dim3(NPIX / 64, MB), 256, 0, stream>>>(Qt, Kt, Sa);
        k_attn_out<<<512, 256, 0, stream>>>(x, gamma, Qt, Kt, V, Sa, out);
    }
}